// Round 12
// baseline (382.409 us; speedup 1.0000x reference)
//
#include <hip/hip_runtime.h>
#include <hip/hip_bf16.h>
#include <stdint.h>

#define DEVI __device__ __forceinline__

typedef short s16x8 __attribute__((ext_vector_type(8)));
typedef short s16x4 __attribute__((ext_vector_type(4)));
typedef float f32x4 __attribute__((ext_vector_type(4)));

static constexpr int BB = 32, SS = 1000, EE = 1024, AA = 512;
static constexpr int MM = BB * SS;  // 32000

// workspace layout (bytes)
static constexpr size_t OFF_X16 = 0;                                   // [M][E] bf16
static constexpr size_t OFF_Q   = OFF_X16 + (size_t)MM * EE * 2;       // [M][A] bf16 (pre-scaled by log2e/sqrt(S))
static constexpr size_t OFF_K   = OFF_Q  + (size_t)MM * AA * 2;        // [M][A] bf16
static constexpr size_t OFF_VT  = OFF_K  + (size_t)MM * AA * 2;       // [B][A][S] bf16
static constexpr size_t OFF_WT  = OFF_VT + (size_t)BB * AA * SS * 2;   // 3 x [A][E] bf16 (z=0:Wq 1:Wk 2:Wv)

DEVI unsigned short f2bf(float f) {  // round-to-nearest-even f32 -> bf16
  union { float f; unsigned int u; } c; c.f = f;
  unsigned int u = c.u + 0x7fffu + ((c.u >> 16) & 1u);
  return (unsigned short)(u >> 16);
}

DEVI void gl_lds16(const void* g, void* l) {  // async global->LDS, 16B/lane, linear dest
  __builtin_amdgcn_global_load_lds(
      (const __attribute__((address_space(1))) unsigned int*)g,
      (__attribute__((address_space(3))) unsigned int*)l, 16, 0, 0);
}

DEVI void wg_barrier() {
  asm volatile("" ::: "memory");
  __builtin_amdgcn_s_barrier();
  asm volatile("" ::: "memory");
}

DEVI float fast_exp2(float x) {
#if __has_builtin(__builtin_amdgcn_exp2f)
  return __builtin_amdgcn_exp2f(x);
#else
  return __builtin_exp2f(x);
#endif
}

// ---------------------------------------------------------------- prep kernels
__global__ __launch_bounds__(256) void x_to_bf16_kernel(const float* __restrict__ x,
                                                        unsigned short* __restrict__ x16) {
  const long n4 = (long)MM * EE / 4;
  long i = (long)blockIdx.x * blockDim.x + threadIdx.x;
  const long stride = (long)gridDim.x * blockDim.x;
  for (; i < n4; i += stride) {
    const float4 v = ((const float4*)x)[i];
    ushort4 o;
    o.x = f2bf(v.x); o.y = f2bf(v.y); o.z = f2bf(v.z); o.w = f2bf(v.w);
    ((ushort4*)x16)[i] = o;
  }
}

// transpose+convert W [E][A] f32 -> WT [A][E] bf16; grid (E/64, A/64, 3)
__global__ __launch_bounds__(256) void wt_kernel(const float* __restrict__ Wq,
                                                 const float* __restrict__ Wk,
                                                 const float* __restrict__ Wv,
                                                 unsigned short* __restrict__ WT) {
  const float* W = (blockIdx.z == 0) ? Wq : (blockIdx.z == 1) ? Wk : Wv;
  unsigned short* out = WT + (size_t)blockIdx.z * AA * EE;
  __shared__ unsigned short t[64][65];
  const int k0 = blockIdx.x * 64, n0 = blockIdx.y * 64;
  #pragma unroll
  for (int i = 0; i < 16; ++i) {
    int idx = i * 256 + threadIdx.x;
    int r = idx >> 6, c = idx & 63;              // r: k-local, c: n-local
    t[r][c] = f2bf(W[(size_t)(k0 + r) * AA + n0 + c]);
  }
  __syncthreads();
  #pragma unroll
  for (int i = 0; i < 16; ++i) {
    int idx = i * 256 + threadIdx.x;
    int r = idx >> 6, c = idx & 63;              // r: n-local, c: k-local
    out[(size_t)(n0 + r) * EE + k0 + c] = t[c][r];
  }
}

// ---------------------------------------------------------------- QKV projection
// C[m][n] = sum_k X16[m][k]*WT[z][n][k]  (NT GEMM), 128x128 tile, BK=64,
// 4 waves (2x2 of 64x64), double-buffered global_load_lds + counted vmcnt.
// Grid: 1D, 3000 blocks, (n,z) INNERMOST: the 12 blocks sharing an X m-panel
// dispatch consecutively -> X panel fetched once per L2, L3-served across XCDs.
__global__ __launch_bounds__(256, 2) void proj_kernel(
    const unsigned short* __restrict__ X16, const unsigned short* __restrict__ WT,
    const float* __restrict__ bq, const float* __restrict__ bk, const float* __restrict__ bv,
    unsigned short* __restrict__ Qo, unsigned short* __restrict__ Ko,
    unsigned short* __restrict__ VTo) {
  constexpr int BK = 64, NKT = EE / BK;  // 16 K-steps
  __shared__ unsigned char lds[65536];   // 2x16KB A | 2x16KB B; reused by epilogue
  unsigned char* ldsA = lds;             // [buf][128 rows][128B]
  unsigned char* ldsB = lds + 32768;
  const int tid = threadIdx.x, lane = tid & 63, wave = tid >> 6;
  const int id = blockIdx.x;
  const int r12 = id % 12;
  const int z = r12 >> 2;                 // 0:Wq 1:Wk 2:Wv
  const int m0 = (id / 12) * 128, n0 = (r12 & 3) * 128;
  const unsigned short* Wz = WT + (size_t)z * AA * EE;

  f32x4 acc[4][4];
  #pragma unroll
  for (int i = 0; i < 4; ++i)
    #pragma unroll
    for (int j = 0; j < 4; ++j) acc[i][j] = f32x4{0.f, 0.f, 0.f, 0.f};

  auto stage = [&](int buf, int kt) {
    #pragma unroll
    for (int i = 0; i < 4; ++i) {
      int c = i * 256 + tid;                 // 1024 16B chunks (A-tile)
      int row = c >> 3;
      int cb = ((c & 7) * 16) ^ ((row & 7) << 4);   // pre-swizzled source column
      gl_lds16(X16 + (size_t)(m0 + row) * EE + kt * BK + (cb >> 1), ldsA + buf * 16384 + c * 16);
    }
    #pragma unroll
    for (int i = 0; i < 4; ++i) {
      int c = i * 256 + tid;
      int row = c >> 3;
      int cb = ((c & 7) * 16) ^ ((row & 7) << 4);
      gl_lds16(Wz + (size_t)(n0 + row) * EE + kt * BK + (cb >> 1), ldsB + buf * 16384 + c * 16);
    }
  };

  auto compute = [&](int buf) {
    #pragma unroll
    for (int kk = 0; kk < 2; ++kk) {
      s16x8 a[4], b[4];
      #pragma unroll
      for (int m = 0; m < 4; ++m) {
        int row = (wave >> 1) * 64 + m * 16 + (lane & 15);
        int cb = (kk * 64 + (lane >> 4) * 16) ^ ((row & 7) << 4);
        a[m] = *(const s16x8*)(ldsA + buf * 16384 + row * 128 + cb);
      }
      #pragma unroll
      for (int n = 0; n < 4; ++n) {
        int row = (wave & 1) * 64 + n * 16 + (lane & 15);
        int cb = (kk * 64 + (lane >> 4) * 16) ^ ((row & 7) << 4);
        b[n] = *(const s16x8*)(ldsB + buf * 16384 + row * 128 + cb);
      }
      #pragma unroll
      for (int m = 0; m < 4; ++m)
        #pragma unroll
        for (int n = 0; n < 4; ++n)
          acc[m][n] = __builtin_amdgcn_mfma_f32_16x16x32_bf16(a[m], b[n], acc[m][n], 0, 0, 0);
    }
  };

  stage(0, 0);
  for (int kt = 0; kt < NKT; ++kt) {
    const int cur = kt & 1;
    if (kt + 1 < NKT) {
      stage(cur ^ 1, kt + 1);
      asm volatile("s_waitcnt vmcnt(8)" ::: "memory");  // current tile done; prefetch stays in flight
    } else {
      asm volatile("s_waitcnt vmcnt(0)" ::: "memory");
    }
    wg_barrier();
    compute(cur);
    wg_barrier();
  }

  // ---- epilogue: bias (+scale for Q), bf16, coalesce via LDS [128][136] tile ----
  const float* bias = (z == 0) ? bq : (z == 1) ? bk : bv;
  const float scale = (z == 0) ? 0.04562280215f : 1.0f;  // log2(e)/sqrt(1000) folded into Q
  unsigned short* T = (unsigned short*)lds;              // 128*136*2 = 34816B
  const int rbase = (wave >> 1) * 64 + (lane >> 4) * 4;  // local row (m / s dim)
  const int cbase = (wave & 1) * 64 + (lane & 15);       // local col (n / a dim)
  float bvals[4];
  #pragma unroll
  for (int n = 0; n < 4; ++n) bvals[n] = bias[n0 + cbase + n * 16];
  #pragma unroll
  for (int m = 0; m < 4; ++m) {
    #pragma unroll
    for (int n = 0; n < 4; ++n) {
      const int cl = cbase + n * 16;
      #pragma unroll
      for (int j = 0; j < 4; ++j) {
        const int rl = rbase + m * 16 + j;
        const unsigned short h = f2bf((acc[m][n][j] + bvals[n]) * scale);
        if (z == 2) T[cl * 136 + rl] = h;   // transposed: [a_local][s_local]
        else        T[rl * 136 + cl] = h;   // natural:    [s_local][a_local]
      }
    }
  }
  wg_barrier();
  #pragma unroll
  for (int i = 0; i < 8; ++i) {
    int c2 = i * 256 + tid;                 // 2048 chunks of 16B
    int r = c2 >> 4, ch = (c2 & 15) * 8;
    s16x8 chunk = *(const s16x8*)&T[r * 136 + ch];
    if (z == 2) {
      // r = a_local, ch.. = s_local. 16B chunk never straddles a batch (8 | 1000).
      const int rowg0 = m0 + ch;
      const int bb2 = rowg0 / SS, ss2 = rowg0 - bb2 * SS;
      *(s16x8*)&VTo[(size_t)bb2 * AA * SS + (size_t)(n0 + r) * SS + ss2] = chunk;
    } else {
      unsigned short* O = (z == 0) ? Qo : Ko;
      *(s16x8*)&O[(size_t)(m0 + r) * AA + n0 + ch] = chunk;
    }
  }
}

// ---------------------------------------------------------------- fused causal attention
// grid 256, 512 threads (8 waves), 128 q-rows/block. b = L&31 (XCD pin: L%8=b%8),
// g = 7-(L>>5). K double-buffered in LDS (74KB total) with prefetch-under-compute.
// V is NOT staged: PV reads V^T directly from global — all 8 waves share the same
// 32KB V tile per iter -> L1-resident; halves LDS traffic (the measured bottleneck:
// 512KB/iter at ~104B/cy == LDS ceiling; MfmaUtil 9.6% with both pipes idle).
__global__ __launch_bounds__(512, 2) void attn_kernel(
    const unsigned short* __restrict__ Qs, const unsigned short* __restrict__ Ks,
    const unsigned short* __restrict__ VT, float* __restrict__ out) {
  constexpr int KVB = 32;
  __shared__ unsigned char ldsK[2][KVB * AA * 2];   // 2 x 32KB, XOR-swizzled rows
  __shared__ unsigned char ldsP[8][16 * 80];        // per-wave P bounce, 10KB

  const int tid = threadIdx.x, lane = tid & 63, wave = tid >> 6;
  const int L = blockIdx.x;
  const int b = L & 31;                      // XCD = L%8 = b%8
  const int g = 7 - (L >> 5);                // q-chunk of 128 rows
  const int q0w = g * 128 + wave * 16;

  // hoisted per-lane K stage offsets (elements); 2048 chunks over 512 threads
  const unsigned short* kbase = Ks + (size_t)b * SS * AA;
  const unsigned short* vbase = VT + (size_t)b * AA * SS;
  unsigned int koff[4];
  #pragma unroll
  for (int i = 0; i < 4; ++i) {
    int c = i * 512 + tid;                   // 2048 chunks
    int r = c >> 6;                          // K row 0..31
    int cb = ((c & 63) * 16) ^ ((r & 7) << 4);
    koff[i] = r * AA + (cb >> 1);
  }
  // per-lane V gather base: a-row (lane&15), k-slot (lane>>4)*8
  const unsigned short* vlane = vbase + (size_t)(lane & 15) * SS + ((lane >> 4) << 3);

  // Q fragments in registers: 16 rows x 512 k
  s16x8 qf[16];
  {
    int qrow = q0w + (lane & 15);
    int qr = qrow < SS ? qrow : SS - 1;
    const unsigned short* qp = Qs + (size_t)(b * SS + qr) * AA + (lane >> 4) * 8;
    #pragma unroll
    for (int f = 0; f < 16; ++f) qf[f] = *(const s16x8*)(qp + f * 32);
  }

  f32x4 o[32];
  #pragma unroll
  for (int n = 0; n < 32; ++n) o[n] = f32x4{0.f, 0.f, 0.f, 0.f};
  float mrun[4], ps[4];
  #pragma unroll
  for (int j = 0; j < 4; ++j) { mrun[j] = -__builtin_inff(); ps[j] = 0.f; }

  const int kmax = (g * 128 + 128 < SS) ? g * 128 + 128 : SS;
  const int ntiles = (kmax + KVB - 1) / KVB;

  auto stageK = [&](int buf, int t) {
    #pragma unroll
    for (int i = 0; i < 4; ++i)
      gl_lds16(kbase + koff[i] + (unsigned)(t * (KVB * AA)),
               &ldsK[buf][(i * 512 + tid) * 16]);
  };

  stageK(0, 0);
  asm volatile("s_waitcnt vmcnt(0)" ::: "memory");
  wg_barrier();

  for (int t = 0; t < ntiles; ++t) {
    const int cur = t & 1;
    const int k0 = t * KVB;
    if (t + 1 < ntiles) stageK(cur ^ 1, t + 1);   // issue K prefetch BEFORE compute

    // ---- QK^T: p[16 rows x 32 keys], 4 independent 8-deep MFMA chains ----
    f32x4 p0a = {0.f, 0.f, 0.f, 0.f}, p0b = {0.f, 0.f, 0.f, 0.f};
    f32x4 p1a = {0.f, 0.f, 0.f, 0.f}, p1b = {0.f, 0.f, 0.f, 0.f};
    {
      const int r0 = lane & 15;
      const int sw = (r0 & 7) << 4;
      const int kb16 = (lane >> 4) * 16;
      const int rb0 = r0 << 10, rb1 = (r0 + 16) << 10;
      #pragma unroll
      for (int f = 0; f < 8; ++f) {
        const int offA = f * 64 + kb16;
        const int offB = (f + 8) * 64 + kb16;
        s16x8 k0A = *(const s16x8*)&ldsK[cur][rb0 + (offA ^ sw)];
        s16x8 k1A = *(const s16x8*)&ldsK[cur][rb1 + (offA ^ sw)];
        s16x8 k0B = *(const s16x8*)&ldsK[cur][rb0 + (offB ^ sw)];
        s16x8 k1B = *(const s16x8*)&ldsK[cur][rb1 + (offB ^ sw)];
        p0a = __builtin_amdgcn_mfma_f32_16x16x32_bf16(qf[f], k0A, p0a, 0, 0, 0);
        p1a = __builtin_amdgcn_mfma_f32_16x16x32_bf16(qf[f], k1A, p1a, 0, 0, 0);
        p0b = __builtin_amdgcn_mfma_f32_16x16x32_bf16(qf[f + 8], k0B, p0b, 0, 0, 0);
        p1b = __builtin_amdgcn_mfma_f32_16x16x32_bf16(qf[f + 8], k1B, p1b, 0, 0, 0);
      }
    }
    f32x4 p0 = p0a + p0b, p1 = p1a + p1b;

    // ---- causal mask + defer-max online softmax ----
    const int kcol = k0 + (lane & 15);
    float lm[4];
    #pragma unroll
    for (int j = 0; j < 4; ++j) {
      const int q = q0w + (lane >> 4) * 4 + j;
      float s0 = p0[j], s1 = p1[j];
      if (kcol > q || kcol >= SS) s0 = -__builtin_inff();
      if (kcol + 16 > q || kcol + 16 >= SS) s1 = -__builtin_inff();
      p0[j] = s0; p1[j] = s1;
      lm[j] = fmaxf(s0, s1);
    }
    const int myneed = (lm[0] > mrun[0] + 8.f) | (lm[1] > mrun[1] + 8.f) |
                       (lm[2] > mrun[2] + 8.f) | (lm[3] > mrun[3] + 8.f);
    if (__any(myneed)) {                        // rare after tile 0
      float rm[4] = {lm[0], lm[1], lm[2], lm[3]};
      #pragma unroll
      for (int st = 1; st <= 8; st <<= 1)
        #pragma unroll
        for (int j = 0; j < 4; ++j) rm[j] = fmaxf(rm[j], __shfl_xor(rm[j], st));
      float corr[4];
      #pragma unroll
      for (int j = 0; j < 4; ++j) {
        const float mnew = fmaxf(mrun[j], rm[j]);
        corr[j] = fast_exp2(mrun[j] - mnew);    // exp2(-inf)=0 on first tile
        mrun[j] = mnew;
        ps[j] *= corr[j];
      }
      #pragma unroll
      for (int n = 0; n < 32; ++n)
        #pragma unroll
        for (int j = 0; j < 4; ++j) o[n][j] *= corr[j];
    }
    #pragma unroll
    for (int j = 0; j < 4; ++j) {               // P = exp2(s - m); per-lane partial sums
      const float e0 = fast_exp2(p0[j] - mrun[j]);
      const float e1 = fast_exp2(p1[j] - mrun[j]);
      ps[j] += e0 + e1;
      p0[j] = e0; p1[j] = e1;
    }

    // ---- P (C-layout) -> bf16 -> wave-private LDS -> A-fragment ----
    {
      unsigned short* pb = (unsigned short*)&ldsP[wave][0];
      const int prow = (lane >> 4) * 4, pc = lane & 15;
      #pragma unroll
      for (int j = 0; j < 4; ++j) {
        pb[(prow + j) * 40 + pc]      = f2bf(p0[j]);
        pb[(prow + j) * 40 + pc + 16] = f2bf(p1[j]);
      }
    }
    s16x8 pa;
    {
      const unsigned char* pp = &ldsP[wave][(lane & 15) * 80 + (lane >> 4) * 16];
      s16x4 lo = *(const s16x4*)pp;
      s16x4 hi = *(const s16x4*)(pp + 8);
      pa = s16x8{lo[0], lo[1], lo[2], lo[3], hi[0], hi[1], hi[2], hi[3]};
    }

    // ---- PV: o[q][a] += P[q][k] * VT[a][k], V read direct from global (L1-shared) ----
    {
      const unsigned short* vtile = vlane + k0;
      #pragma unroll
      for (int ng = 0; ng < 4; ++ng) {
        s16x8 vb[8];
        #pragma unroll
        for (int u = 0; u < 8; ++u)
          vb[u] = *(const s16x8*)(vtile + (size_t)((ng * 8 + u) * 16) * SS);
        #pragma unroll
        for (int u = 0; u < 8; ++u)
          o[ng * 8 + u] = __builtin_amdgcn_mfma_f32_16x16x32_bf16(pa, vb[u], o[ng * 8 + u], 0, 0, 0);
      }
    }

    asm volatile("s_waitcnt vmcnt(0)" ::: "memory");  // K prefetch landed (covered by compute)
    wg_barrier();                                     // tile cur fully consumed by all waves
  }

  // ---- finalize: reduce per-lane partial sums, divide, store fp32 ----
  #pragma unroll
  for (int st = 1; st <= 8; st <<= 1)
    #pragma unroll
    for (int j = 0; j < 4; ++j) ps[j] += __shfl_xor(ps[j], st);
  #pragma unroll
  for (int j = 0; j < 4; ++j) {
    const int q = q0w + (lane >> 4) * 4 + j;
    if (q < SS) {
      const float inv = 1.0f / ps[j];
      float* op = out + (size_t)(b * SS + q) * AA + (lane & 15);
      #pragma unroll
      for (int n = 0; n < 32; ++n) op[n * 16] = o[n][j] * inv;
    }
  }
}

// ---------------------------------------------------------------- launch
extern "C" void kernel_launch(void* const* d_in, const int* in_sizes, int n_in,
                              void* d_out, int out_size, void* d_ws, size_t ws_size,
                              hipStream_t stream) {
  const float* x  = (const float*)d_in[0];
  const float* Wk = (const float*)d_in[1];
  const float* bk = (const float*)d_in[2];
  const float* Wq = (const float*)d_in[3];
  const float* bq = (const float*)d_in[4];
  const float* Wv = (const float*)d_in[5];
  const float* bv = (const float*)d_in[6];

  char* ws = (char*)d_ws;
  unsigned short* X16 = (unsigned short*)(ws + OFF_X16);
  unsigned short* Qw  = (unsigned short*)(ws + OFF_Q);
  unsigned short* Kw  = (unsigned short*)(ws + OFF_K);
  unsigned short* VTw = (unsigned short*)(ws + OFF_VT);
  unsigned short* WT  = (unsigned short*)(ws + OFF_WT);

  x_to_bf16_kernel<<<dim3(2048), dim3(256), 0, stream>>>(x, X16);
  wt_kernel<<<dim3(EE / 64, AA / 64, 3), dim3(256), 0, stream>>>(Wq, Wk, Wv, WT);
  proj_kernel<<<dim3(3000), dim3(256), 0, stream>>>(
      X16, WT, bq, bk, bv, Qw, Kw, VTw);
  attn_kernel<<<dim3(256), dim3(512), 0, stream>>>(Qw, Kw, VTw, (float*)d_out);
}

// Round 16
// 318.103 us; speedup vs baseline: 1.2022x; 1.2022x over previous
//
#include <hip/hip_runtime.h>
#include <hip/hip_bf16.h>
#include <stdint.h>

#define DEVI __device__ __forceinline__

typedef short s16x8 __attribute__((ext_vector_type(8)));
typedef short s16x4 __attribute__((ext_vector_type(4)));
typedef float f32x4 __attribute__((ext_vector_type(4)));

static constexpr int BB = 32, SS = 1000, EE = 1024, AA = 512;
static constexpr int MM = BB * SS;  // 32000

// workspace layout (bytes)
static constexpr size_t OFF_X16 = 0;                                   // [M][E] bf16
static constexpr size_t OFF_Q   = OFF_X16 + (size_t)MM * EE * 2;       // [M][A] bf16 (pre-scaled by log2e/sqrt(S))
static constexpr size_t OFF_K   = OFF_Q  + (size_t)MM * AA * 2;        // [M][A] bf16
static constexpr size_t OFF_VT  = OFF_K  + (size_t)MM * AA * 2;       // [B][A][S] bf16
static constexpr size_t OFF_WT  = OFF_VT + (size_t)BB * AA * SS * 2;   // 3 x [A][E] bf16 (z=0:Wq 1:Wk 2:Wv)

DEVI unsigned short f2bf(float f) {  // round-to-nearest-even f32 -> bf16
  union { float f; unsigned int u; } c; c.f = f;
  unsigned int u = c.u + 0x7fffu + ((c.u >> 16) & 1u);
  return (unsigned short)(u >> 16);
}

DEVI void gl_lds16(const void* g, void* l) {  // async global->LDS, 16B/lane, linear dest
  __builtin_amdgcn_global_load_lds(
      (const __attribute__((address_space(1))) unsigned int*)g,
      (__attribute__((address_space(3))) unsigned int*)l, 16, 0, 0);
}

DEVI void wg_barrier() {
  asm volatile("" ::: "memory");
  __builtin_amdgcn_s_barrier();
  asm volatile("" ::: "memory");
}

DEVI float fast_exp2(float x) {
#if __has_builtin(__builtin_amdgcn_exp2f)
  return __builtin_amdgcn_exp2f(x);
#else
  return __builtin_exp2f(x);
#endif
}

// ---------------------------------------------------------------- prep kernels
__global__ __launch_bounds__(256) void x_to_bf16_kernel(const float* __restrict__ x,
                                                        unsigned short* __restrict__ x16) {
  const long n4 = (long)MM * EE / 4;
  long i = (long)blockIdx.x * blockDim.x + threadIdx.x;
  const long stride = (long)gridDim.x * blockDim.x;
  for (; i < n4; i += stride) {
    const float4 v = ((const float4*)x)[i];
    ushort4 o;
    o.x = f2bf(v.x); o.y = f2bf(v.y); o.z = f2bf(v.z); o.w = f2bf(v.w);
    ((ushort4*)x16)[i] = o;
  }
}

// transpose+convert W [E][A] f32 -> WT [A][E] bf16; grid (E/64, A/64, 3)
__global__ __launch_bounds__(256) void wt_kernel(const float* __restrict__ Wq,
                                                 const float* __restrict__ Wk,
                                                 const float* __restrict__ Wv,
                                                 unsigned short* __restrict__ WT) {
  const float* W = (blockIdx.z == 0) ? Wq : (blockIdx.z == 1) ? Wk : Wv;
  unsigned short* out = WT + (size_t)blockIdx.z * AA * EE;
  __shared__ unsigned short t[64][65];
  const int k0 = blockIdx.x * 64, n0 = blockIdx.y * 64;
  #pragma unroll
  for (int i = 0; i < 16; ++i) {
    int idx = i * 256 + threadIdx.x;
    int r = idx >> 6, c = idx & 63;              // r: k-local, c: n-local
    t[r][c] = f2bf(W[(size_t)(k0 + r) * AA + n0 + c]);
  }
  __syncthreads();
  #pragma unroll
  for (int i = 0; i < 16; ++i) {
    int idx = i * 256 + threadIdx.x;
    int r = idx >> 6, c = idx & 63;              // r: n-local, c: k-local
    out[(size_t)(n0 + r) * EE + k0 + c] = t[c][r];
  }
}

// ---------------------------------------------------------------- QKV projection
// C[m][n] = sum_k X16[m][k]*WT[z][n][k]  (NT GEMM), 128x128 tile, BK=64,
// 4 waves (2x2 of 64x64), double-buffered global_load_lds + counted vmcnt.
// Grid: 1D, 3000 blocks, (n,z) INNERMOST: the 12 blocks sharing an X m-panel
// dispatch consecutively -> X panel fetched once per L2, L3-served across XCDs.
__global__ __launch_bounds__(256, 2) void proj_kernel(
    const unsigned short* __restrict__ X16, const unsigned short* __restrict__ WT,
    const float* __restrict__ bq, const float* __restrict__ bk, const float* __restrict__ bv,
    unsigned short* __restrict__ Qo, unsigned short* __restrict__ Ko,
    unsigned short* __restrict__ VTo) {
  constexpr int BK = 64, NKT = EE / BK;  // 16 K-steps
  __shared__ unsigned char lds[65536];   // 2x16KB A | 2x16KB B; reused by epilogue
  unsigned char* ldsA = lds;             // [buf][128 rows][128B]
  unsigned char* ldsB = lds + 32768;
  const int tid = threadIdx.x, lane = tid & 63, wave = tid >> 6;
  const int id = blockIdx.x;
  const int r12 = id % 12;
  const int z = r12 >> 2;                 // 0:Wq 1:Wk 2:Wv
  const int m0 = (id / 12) * 128, n0 = (r12 & 3) * 128;
  const unsigned short* Wz = WT + (size_t)z * AA * EE;

  f32x4 acc[4][4];
  #pragma unroll
  for (int i = 0; i < 4; ++i)
    #pragma unroll
    for (int j = 0; j < 4; ++j) acc[i][j] = f32x4{0.f, 0.f, 0.f, 0.f};

  auto stage = [&](int buf, int kt) {
    #pragma unroll
    for (int i = 0; i < 4; ++i) {
      int c = i * 256 + tid;                 // 1024 16B chunks (A-tile)
      int row = c >> 3;
      int cb = ((c & 7) * 16) ^ ((row & 7) << 4);   // pre-swizzled source column
      gl_lds16(X16 + (size_t)(m0 + row) * EE + kt * BK + (cb >> 1), ldsA + buf * 16384 + c * 16);
    }
    #pragma unroll
    for (int i = 0; i < 4; ++i) {
      int c = i * 256 + tid;
      int row = c >> 3;
      int cb = ((c & 7) * 16) ^ ((row & 7) << 4);
      gl_lds16(Wz + (size_t)(n0 + row) * EE + kt * BK + (cb >> 1), ldsB + buf * 16384 + c * 16);
    }
  };

  auto compute = [&](int buf) {
    #pragma unroll
    for (int kk = 0; kk < 2; ++kk) {
      s16x8 a[4], b[4];
      #pragma unroll
      for (int m = 0; m < 4; ++m) {
        int row = (wave >> 1) * 64 + m * 16 + (lane & 15);
        int cb = (kk * 64 + (lane >> 4) * 16) ^ ((row & 7) << 4);
        a[m] = *(const s16x8*)(ldsA + buf * 16384 + row * 128 + cb);
      }
      #pragma unroll
      for (int n = 0; n < 4; ++n) {
        int row = (wave & 1) * 64 + n * 16 + (lane & 15);
        int cb = (kk * 64 + (lane >> 4) * 16) ^ ((row & 7) << 4);
        b[n] = *(const s16x8*)(ldsB + buf * 16384 + row * 128 + cb);
      }
      #pragma unroll
      for (int m = 0; m < 4; ++m)
        #pragma unroll
        for (int n = 0; n < 4; ++n)
          acc[m][n] = __builtin_amdgcn_mfma_f32_16x16x32_bf16(a[m], b[n], acc[m][n], 0, 0, 0);
    }
  };

  stage(0, 0);
  for (int kt = 0; kt < NKT; ++kt) {
    const int cur = kt & 1;
    if (kt + 1 < NKT) {
      stage(cur ^ 1, kt + 1);
      asm volatile("s_waitcnt vmcnt(8)" ::: "memory");  // current tile done; prefetch stays in flight
    } else {
      asm volatile("s_waitcnt vmcnt(0)" ::: "memory");
    }
    wg_barrier();
    compute(cur);
    wg_barrier();
  }

  // ---- epilogue: bias (+scale for Q), bf16, coalesce via LDS [128][136] tile ----
  const float* bias = (z == 0) ? bq : (z == 1) ? bk : bv;
  const float scale = (z == 0) ? 0.04562280215f : 1.0f;  // log2(e)/sqrt(1000) folded into Q
  unsigned short* T = (unsigned short*)lds;              // 128*136*2 = 34816B
  const int rbase = (wave >> 1) * 64 + (lane >> 4) * 4;  // local row (m / s dim)
  const int cbase = (wave & 1) * 64 + (lane & 15);       // local col (n / a dim)
  float bvals[4];
  #pragma unroll
  for (int n = 0; n < 4; ++n) bvals[n] = bias[n0 + cbase + n * 16];
  #pragma unroll
  for (int m = 0; m < 4; ++m) {
    #pragma unroll
    for (int n = 0; n < 4; ++n) {
      const int cl = cbase + n * 16;
      #pragma unroll
      for (int j = 0; j < 4; ++j) {
        const int rl = rbase + m * 16 + j;
        const unsigned short h = f2bf((acc[m][n][j] + bvals[n]) * scale);
        if (z == 2) T[cl * 136 + rl] = h;   // transposed: [a_local][s_local]
        else        T[rl * 136 + cl] = h;   // natural:    [s_local][a_local]
      }
    }
  }
  wg_barrier();
  #pragma unroll
  for (int i = 0; i < 8; ++i) {
    int c2 = i * 256 + tid;                 // 2048 chunks of 16B
    int r = c2 >> 4, ch = (c2 & 15) * 8;
    s16x8 chunk = *(const s16x8*)&T[r * 136 + ch];
    if (z == 2) {
      // r = a_local, ch.. = s_local. 16B chunk never straddles a batch (8 | 1000).
      const int rowg0 = m0 + ch;
      const int bb2 = rowg0 / SS, ss2 = rowg0 - bb2 * SS;
      *(s16x8*)&VTo[(size_t)bb2 * AA * SS + (size_t)(n0 + r) * SS + ss2] = chunk;
    } else {
      unsigned short* O = (z == 0) ? Qo : Ko;
      *(s16x8*)&O[(size_t)(m0 + r) * AA + n0 + ch] = chunk;
    }
  }
}

// ---------------------------------------------------------------- fused causal attention
// grid 256, 512 threads (8 waves), 128 q-rows/block. b = L&31 (XCD pin: L%8=b%8),
// g = 7-(L>>5). One 64KB K/V stage serves 128 q-rows. K+V double-buffered
// (138KB LDS, 1 block/CU, 8 waves = 2/SIMD): stage(t+1) issued BEFORE compute(t),
// single vmcnt(0)+barrier per tile -> load latency hidden under compute.
__global__ __launch_bounds__(512, 2) void attn_kernel(
    const unsigned short* __restrict__ Qs, const unsigned short* __restrict__ Ks,
    const unsigned short* __restrict__ VT, float* __restrict__ out) {
  constexpr int KVB = 32;
  __shared__ unsigned char ldsK[2][KVB * AA * 2];   // 2 x 32KB, XOR-swizzled rows
  __shared__ unsigned char ldsV[2][AA * KVB * 2];   // 2 x 32KB, pair-layout swizzled
  __shared__ unsigned char ldsP[8][16 * 80];        // per-wave P bounce, 10KB

  const int tid = threadIdx.x, lane = tid & 63, wave = tid >> 6;
  const int L = blockIdx.x;
  const int b = L & 31;                      // XCD = L%8 = b%8
  const int g = 7 - (L >> 5);                // q-chunk of 128 rows
  const int q0w = g * 128 + wave * 16;

  // hoisted per-lane stage offsets (elements); 4096 chunks over 512 threads
  const unsigned short* kbase = Ks + (size_t)b * SS * AA;
  const unsigned short* vbase = VT + (size_t)b * AA * SS;
  unsigned int koff[4], voff[4];
  #pragma unroll
  for (int i = 0; i < 4; ++i) {
    int c = i * 512 + tid;                   // 2048 chunks
    int r = c >> 6;                          // K row 0..31
    int cb = ((c & 63) * 16) ^ ((r & 7) << 4);
    koff[i] = r * AA + (cb >> 1);
    int pair = c >> 3;
    int within = (c & 7) * 16;
    int half = within >> 6;
    int kb = (within & 63) ^ ((pair & 3) << 4);
    int a_ = pair * 2 + half;
    voff[i] = a_ * SS + (kb >> 1);
  }

  // Q fragments in registers: 16 rows x 512 k
  s16x8 qf[16];
  {
    int qrow = q0w + (lane & 15);
    int qr = qrow < SS ? qrow : SS - 1;
    const unsigned short* qp = Qs + (size_t)(b * SS + qr) * AA + (lane >> 4) * 8;
    #pragma unroll
    for (int f = 0; f < 16; ++f) qf[f] = *(const s16x8*)(qp + f * 32);
  }

  f32x4 o[32];
  #pragma unroll
  for (int n = 0; n < 32; ++n) o[n] = f32x4{0.f, 0.f, 0.f, 0.f};
  float mrun[4], ps[4];
  #pragma unroll
  for (int j = 0; j < 4; ++j) { mrun[j] = -__builtin_inff(); ps[j] = 0.f; }

  const int kmax = (g * 128 + 128 < SS) ? g * 128 + 128 : SS;
  const int ntiles = (kmax + KVB - 1) / KVB;

  auto stageKV = [&](int buf, int t) {
    #pragma unroll
    for (int i = 0; i < 4; ++i)
      gl_lds16(kbase + koff[i] + (unsigned)(t * (KVB * AA)),
               &ldsK[buf][(i * 512 + tid) * 16]);
    #pragma unroll
    for (int i = 0; i < 4; ++i)
      gl_lds16(vbase + voff[i] + (unsigned)(t * KVB),
               &ldsV[buf][(i * 512 + tid) * 16]);
  };

  stageKV(0, 0);
  asm volatile("s_waitcnt vmcnt(0)" ::: "memory");
  wg_barrier();

  for (int t = 0; t < ntiles; ++t) {
    const int cur = t & 1;
    const int k0 = t * KVB;
    if (t + 1 < ntiles) stageKV(cur ^ 1, t + 1);   // issue prefetch BEFORE compute

    // ---- QK^T: p[16 rows x 32 keys], 4 independent 8-deep MFMA chains ----
    f32x4 p0a = {0.f, 0.f, 0.f, 0.f}, p0b = {0.f, 0.f, 0.f, 0.f};
    f32x4 p1a = {0.f, 0.f, 0.f, 0.f}, p1b = {0.f, 0.f, 0.f, 0.f};
    {
      const int r0 = lane & 15;
      const int sw = (r0 & 7) << 4;
      const int kb16 = (lane >> 4) * 16;
      const int rb0 = r0 << 10, rb1 = (r0 + 16) << 10;
      #pragma unroll
      for (int f = 0; f < 8; ++f) {
        const int offA = f * 64 + kb16;
        const int offB = (f + 8) * 64 + kb16;
        s16x8 k0A = *(const s16x8*)&ldsK[cur][rb0 + (offA ^ sw)];
        s16x8 k1A = *(const s16x8*)&ldsK[cur][rb1 + (offA ^ sw)];
        s16x8 k0B = *(const s16x8*)&ldsK[cur][rb0 + (offB ^ sw)];
        s16x8 k1B = *(const s16x8*)&ldsK[cur][rb1 + (offB ^ sw)];
        p0a = __builtin_amdgcn_mfma_f32_16x16x32_bf16(qf[f], k0A, p0a, 0, 0, 0);
        p1a = __builtin_amdgcn_mfma_f32_16x16x32_bf16(qf[f], k1A, p1a, 0, 0, 0);
        p0b = __builtin_amdgcn_mfma_f32_16x16x32_bf16(qf[f + 8], k0B, p0b, 0, 0, 0);
        p1b = __builtin_amdgcn_mfma_f32_16x16x32_bf16(qf[f + 8], k1B, p1b, 0, 0, 0);
      }
    }
    f32x4 p0 = p0a + p0b, p1 = p1a + p1b;

    // ---- causal mask + defer-max online softmax ----
    const int kcol = k0 + (lane & 15);
    float lm[4];
    #pragma unroll
    for (int j = 0; j < 4; ++j) {
      const int q = q0w + (lane >> 4) * 4 + j;
      float s0 = p0[j], s1 = p1[j];
      if (kcol > q || kcol >= SS) s0 = -__builtin_inff();
      if (kcol + 16 > q || kcol + 16 >= SS) s1 = -__builtin_inff();
      p0[j] = s0; p1[j] = s1;
      lm[j] = fmaxf(s0, s1);
    }
    const int myneed = (lm[0] > mrun[0] + 8.f) | (lm[1] > mrun[1] + 8.f) |
                       (lm[2] > mrun[2] + 8.f) | (lm[3] > mrun[3] + 8.f);
    if (__any(myneed)) {                        // rare after tile 0
      float rm[4] = {lm[0], lm[1], lm[2], lm[3]};
      #pragma unroll
      for (int st = 1; st <= 8; st <<= 1)
        #pragma unroll
        for (int j = 0; j < 4; ++j) rm[j] = fmaxf(rm[j], __shfl_xor(rm[j], st));
      float corr[4];
      #pragma unroll
      for (int j = 0; j < 4; ++j) {
        const float mnew = fmaxf(mrun[j], rm[j]);
        corr[j] = fast_exp2(mrun[j] - mnew);    // exp2(-inf)=0 on first tile
        mrun[j] = mnew;
        ps[j] *= corr[j];
      }
      #pragma unroll
      for (int n = 0; n < 32; ++n)
        #pragma unroll
        for (int j = 0; j < 4; ++j) o[n][j] *= corr[j];
    }
    #pragma unroll
    for (int j = 0; j < 4; ++j) {               // P = exp2(s - m); per-lane partial sums
      const float e0 = fast_exp2(p0[j] - mrun[j]);
      const float e1 = fast_exp2(p1[j] - mrun[j]);
      ps[j] += e0 + e1;
      p0[j] = e0; p1[j] = e1;
    }

    // ---- P (C-layout) -> bf16 -> wave-private LDS -> A-fragment ----
    {
      unsigned short* pb = (unsigned short*)&ldsP[wave][0];
      const int prow = (lane >> 4) * 4, pc = lane & 15;
      #pragma unroll
      for (int j = 0; j < 4; ++j) {
        pb[(prow + j) * 40 + pc]      = f2bf(p0[j]);
        pb[(prow + j) * 40 + pc + 16] = f2bf(p1[j]);
      }
    }
    s16x8 pa;
    {
      const unsigned char* pp = &ldsP[wave][(lane & 15) * 80 + (lane >> 4) * 16];
      s16x4 lo = *(const s16x4*)pp;
      s16x4 hi = *(const s16x4*)(pp + 8);
      pa = s16x8{lo[0], lo[1], lo[2], lo[3], hi[0], hi[1], hi[2], hi[3]};
    }

    // ---- PV: o[q][a] += P[q][k] * VT[a][k] ----
    #pragma unroll
    for (int n = 0; n < 32; ++n) {
      const int a_ = n * 16 + (lane & 15);
      const int pair = a_ >> 1;
      const int off = pair * 128 + (a_ & 1) * 64 + (((lane >> 4) * 16) ^ ((pair & 3) << 4));
      s16x8 vb = *(const s16x8*)&ldsV[cur][off];
      o[n] = __builtin_amdgcn_mfma_f32_16x16x32_bf16(pa, vb, o[n], 0, 0, 0);
    }

    asm volatile("s_waitcnt vmcnt(0)" ::: "memory");  // prefetch landed (covered by compute)
    wg_barrier();                                     // tile cur fully consumed by all waves
  }

  // ---- finalize: reduce per-lane partial sums, divide, store fp32 ----
  #pragma unroll
  for (int st = 1; st <= 8; st <<= 1)
    #pragma unroll
    for (int j = 0; j < 4; ++j) ps[j] += __shfl_xor(ps[j], st);
  #pragma unroll
  for (int j = 0; j < 4; ++j) {
    const int q = q0w + (lane >> 4) * 4 + j;
    if (q < SS) {
      const float inv = 1.0f / ps[j];
      float* op = out + (size_t)(b * SS + q) * AA + (lane & 15);
      #pragma unroll
      for (int n = 0; n < 32; ++n) op[n * 16] = o[n][j] * inv;
    }
  }
}

// ---------------------------------------------------------------- launch
extern "C" void kernel_launch(void* const* d_in, const int* in_sizes, int n_in,
                              void* d_out, int out_size, void* d_ws, size_t ws_size,
                              hipStream_t stream) {
  const float* x  = (const float*)d_in[0];
  const float* Wk = (const float*)d_in[1];
  const float* bk = (const float*)d_in[2];
  const float* Wq = (const float*)d_in[3];
  const float* bq = (const float*)d_in[4];
  const float* Wv = (const float*)d_in[5];
  const float* bv = (const float*)d_in[6];

  char* ws = (char*)d_ws;
  unsigned short* X16 = (unsigned short*)(ws + OFF_X16);
  unsigned short* Qw  = (unsigned short*)(ws + OFF_Q);
  unsigned short* Kw  = (unsigned short*)(ws + OFF_K);
  unsigned short* VTw = (unsigned short*)(ws + OFF_VT);
  unsigned short* WT  = (unsigned short*)(ws + OFF_WT);

  x_to_bf16_kernel<<<dim3(2048), dim3(256), 0, stream>>>(x, X16);
  wt_kernel<<<dim3(EE / 64, AA / 64, 3), dim3(256), 0, stream>>>(Wq, Wk, Wv, WT);
  proj_kernel<<<dim3(3000), dim3(256), 0, stream>>>(
      X16, WT, bq, bk, bv, Qw, Kw, VTw);
  attn_kernel<<<dim3(256), dim3(512), 0, stream>>>(Qw, Kw, VTw, (float*)d_out);
}

// Round 17
// 306.461 us; speedup vs baseline: 1.2478x; 1.0380x over previous
//
#include <hip/hip_runtime.h>
#include <hip/hip_bf16.h>
#include <stdint.h>

#define DEVI __device__ __forceinline__

typedef short s16x8 __attribute__((ext_vector_type(8)));
typedef short s16x4 __attribute__((ext_vector_type(4)));
typedef float f32x4 __attribute__((ext_vector_type(4)));

static constexpr int BB = 32, SS = 1000, EE = 1024, AA = 512;
static constexpr int MM = BB * SS;  // 32000

// workspace layout (bytes)
static constexpr size_t OFF_X16 = 0;                                   // [M][E] bf16
static constexpr size_t OFF_Q   = OFF_X16 + (size_t)MM * EE * 2;       // [M][A] bf16 (pre-scaled by log2e/sqrt(S))
static constexpr size_t OFF_K   = OFF_Q  + (size_t)MM * AA * 2;        // [M][A] bf16
static constexpr size_t OFF_VT  = OFF_K  + (size_t)MM * AA * 2;       // [B][A][S] bf16
static constexpr size_t OFF_WT  = OFF_VT + (size_t)BB * AA * SS * 2;   // 3 x [A][E] bf16 (z=0:Wq 1:Wk 2:Wv)

DEVI unsigned short f2bf(float f) {  // round-to-nearest-even f32 -> bf16
  union { float f; unsigned int u; } c; c.f = f;
  unsigned int u = c.u + 0x7fffu + ((c.u >> 16) & 1u);
  return (unsigned short)(u >> 16);
}

DEVI void gl_lds16(const void* g, void* l) {  // async global->LDS, 16B/lane, linear dest
  __builtin_amdgcn_global_load_lds(
      (const __attribute__((address_space(1))) unsigned int*)g,
      (__attribute__((address_space(3))) unsigned int*)l, 16, 0, 0);
}

DEVI void wg_barrier() {
  asm volatile("" ::: "memory");
  __builtin_amdgcn_s_barrier();
  asm volatile("" ::: "memory");
}

DEVI float fast_exp2(float x) {
#if __has_builtin(__builtin_amdgcn_exp2f)
  return __builtin_amdgcn_exp2f(x);
#else
  return __builtin_exp2f(x);
#endif
}

// ---------------------------------------------------------------- prep kernels
__global__ __launch_bounds__(256) void x_to_bf16_kernel(const float* __restrict__ x,
                                                        unsigned short* __restrict__ x16) {
  const long n4 = (long)MM * EE / 4;
  long i = (long)blockIdx.x * blockDim.x + threadIdx.x;
  const long stride = (long)gridDim.x * blockDim.x;
  for (; i < n4; i += stride) {
    const float4 v = ((const float4*)x)[i];
    ushort4 o;
    o.x = f2bf(v.x); o.y = f2bf(v.y); o.z = f2bf(v.z); o.w = f2bf(v.w);
    ((ushort4*)x16)[i] = o;
  }
}

// transpose+convert W [E][A] f32 -> WT [A][E] bf16; grid (E/64, A/64, 3)
__global__ __launch_bounds__(256) void wt_kernel(const float* __restrict__ Wq,
                                                 const float* __restrict__ Wk,
                                                 const float* __restrict__ Wv,
                                                 unsigned short* __restrict__ WT) {
  const float* W = (blockIdx.z == 0) ? Wq : (blockIdx.z == 1) ? Wk : Wv;
  unsigned short* out = WT + (size_t)blockIdx.z * AA * EE;
  __shared__ unsigned short t[64][65];
  const int k0 = blockIdx.x * 64, n0 = blockIdx.y * 64;
  #pragma unroll
  for (int i = 0; i < 16; ++i) {
    int idx = i * 256 + threadIdx.x;
    int r = idx >> 6, c = idx & 63;              // r: k-local, c: n-local
    t[r][c] = f2bf(W[(size_t)(k0 + r) * AA + n0 + c]);
  }
  __syncthreads();
  #pragma unroll
  for (int i = 0; i < 16; ++i) {
    int idx = i * 256 + threadIdx.x;
    int r = idx >> 6, c = idx & 63;              // r: n-local, c: k-local
    out[(size_t)(n0 + r) * EE + k0 + c] = t[c][r];
  }
}

// ---------------------------------------------------------------- QKV projection
// C[m][n] = sum_k X16[m][k]*WT[z][n][k]  (NT GEMM), 128x128 tile, BK=64,
// 4 waves (2x2 of 64x64), double-buffered global_load_lds + counted vmcnt.
// Grid: 1D, 3000 blocks, (n,z) INNERMOST: the 12 blocks sharing an X m-panel
// dispatch consecutively -> X panel fetched once per L2, L3-served across XCDs.
__global__ __launch_bounds__(256, 2) void proj_kernel(
    const unsigned short* __restrict__ X16, const unsigned short* __restrict__ WT,
    const float* __restrict__ bq, const float* __restrict__ bk, const float* __restrict__ bv,
    unsigned short* __restrict__ Qo, unsigned short* __restrict__ Ko,
    unsigned short* __restrict__ VTo) {
  constexpr int BK = 64, NKT = EE / BK;  // 16 K-steps
  __shared__ unsigned char lds[65536];   // 2x16KB A | 2x16KB B; reused by epilogue
  unsigned char* ldsA = lds;             // [buf][128 rows][128B]
  unsigned char* ldsB = lds + 32768;
  const int tid = threadIdx.x, lane = tid & 63, wave = tid >> 6;
  const int id = blockIdx.x;
  const int r12 = id % 12;
  const int z = r12 >> 2;                 // 0:Wq 1:Wk 2:Wv
  const int m0 = (id / 12) * 128, n0 = (r12 & 3) * 128;
  const unsigned short* Wz = WT + (size_t)z * AA * EE;

  f32x4 acc[4][4];
  #pragma unroll
  for (int i = 0; i < 4; ++i)
    #pragma unroll
    for (int j = 0; j < 4; ++j) acc[i][j] = f32x4{0.f, 0.f, 0.f, 0.f};

  auto stage = [&](int buf, int kt) {
    #pragma unroll
    for (int i = 0; i < 4; ++i) {
      int c = i * 256 + tid;                 // 1024 16B chunks (A-tile)
      int row = c >> 3;
      int cb = ((c & 7) * 16) ^ ((row & 7) << 4);   // pre-swizzled source column
      gl_lds16(X16 + (size_t)(m0 + row) * EE + kt * BK + (cb >> 1), ldsA + buf * 16384 + c * 16);
    }
    #pragma unroll
    for (int i = 0; i < 4; ++i) {
      int c = i * 256 + tid;
      int row = c >> 3;
      int cb = ((c & 7) * 16) ^ ((row & 7) << 4);
      gl_lds16(Wz + (size_t)(n0 + row) * EE + kt * BK + (cb >> 1), ldsB + buf * 16384 + c * 16);
    }
  };

  auto compute = [&](int buf) {
    #pragma unroll
    for (int kk = 0; kk < 2; ++kk) {
      s16x8 a[4], b[4];
      #pragma unroll
      for (int m = 0; m < 4; ++m) {
        int row = (wave >> 1) * 64 + m * 16 + (lane & 15);
        int cb = (kk * 64 + (lane >> 4) * 16) ^ ((row & 7) << 4);
        a[m] = *(const s16x8*)(ldsA + buf * 16384 + row * 128 + cb);
      }
      #pragma unroll
      for (int n = 0; n < 4; ++n) {
        int row = (wave & 1) * 64 + n * 16 + (lane & 15);
        int cb = (kk * 64 + (lane >> 4) * 16) ^ ((row & 7) << 4);
        b[n] = *(const s16x8*)(ldsB + buf * 16384 + row * 128 + cb);
      }
      #pragma unroll
      for (int m = 0; m < 4; ++m)
        #pragma unroll
        for (int n = 0; n < 4; ++n)
          acc[m][n] = __builtin_amdgcn_mfma_f32_16x16x32_bf16(a[m], b[n], acc[m][n], 0, 0, 0);
    }
  };

  stage(0, 0);
  for (int kt = 0; kt < NKT; ++kt) {
    const int cur = kt & 1;
    if (kt + 1 < NKT) {
      stage(cur ^ 1, kt + 1);
      asm volatile("s_waitcnt vmcnt(8)" ::: "memory");  // current tile done; prefetch stays in flight
    } else {
      asm volatile("s_waitcnt vmcnt(0)" ::: "memory");
    }
    wg_barrier();
    compute(cur);
    wg_barrier();
  }

  // ---- epilogue: bias (+scale for Q), bf16, coalesce via LDS [128][136] tile ----
  const float* bias = (z == 0) ? bq : (z == 1) ? bk : bv;
  const float scale = (z == 0) ? 0.04562280215f : 1.0f;  // log2(e)/sqrt(1000) folded into Q
  unsigned short* T = (unsigned short*)lds;              // 128*136*2 = 34816B
  const int rbase = (wave >> 1) * 64 + (lane >> 4) * 4;  // local row (m / s dim)
  const int cbase = (wave & 1) * 64 + (lane & 15);       // local col (n / a dim)
  float bvals[4];
  #pragma unroll
  for (int n = 0; n < 4; ++n) bvals[n] = bias[n0 + cbase + n * 16];
  #pragma unroll
  for (int m = 0; m < 4; ++m) {
    #pragma unroll
    for (int n = 0; n < 4; ++n) {
      const int cl = cbase + n * 16;
      #pragma unroll
      for (int j = 0; j < 4; ++j) {
        const int rl = rbase + m * 16 + j;
        const unsigned short h = f2bf((acc[m][n][j] + bvals[n]) * scale);
        if (z == 2) T[cl * 136 + rl] = h;   // transposed: [a_local][s_local]
        else        T[rl * 136 + cl] = h;   // natural:    [s_local][a_local]
      }
    }
  }
  wg_barrier();
  #pragma unroll
  for (int i = 0; i < 8; ++i) {
    int c2 = i * 256 + tid;                 // 2048 chunks of 16B
    int r = c2 >> 4, ch = (c2 & 15) * 8;
    s16x8 chunk = *(const s16x8*)&T[r * 136 + ch];
    if (z == 2) {
      // r = a_local, ch.. = s_local. 16B chunk never straddles a batch (8 | 1000).
      const int rowg0 = m0 + ch;
      const int bb2 = rowg0 / SS, ss2 = rowg0 - bb2 * SS;
      *(s16x8*)&VTo[(size_t)bb2 * AA * SS + (size_t)(n0 + r) * SS + ss2] = chunk;
    } else {
      unsigned short* O = (z == 0) ? Qo : Ko;
      *(s16x8*)&O[(size_t)(m0 + r) * AA + n0 + ch] = chunk;
    }
  }
}

// ---------------------------------------------------------------- fused causal attention
// TRIANGLE-FOLD balance: 16 q-chunks of 64 rows; block i (i=L>>5) owns chunk i
// (EARLY, waves 4-7) + chunk 15-i (LATE, waves 0-3). Block loop = 2*(16-i) tiles;
// early waves compute only their first 2*(i+1) tiles, then keep staging+barriers
// (uniform loop count, no barrier divergence). If tile cost scales with active
// waves (LDS-issue-bound), CU busy ~= const 17T across i (vs 32T makespan before).
// b = L&31 (XCD pin: L%8=b%8); long blocks (i=0) dispatch first.
// K+V double-buffered (138KB LDS, 1 block/CU, 8 waves): stage(t+1) BEFORE compute(t).
__global__ __launch_bounds__(512, 2) void attn_kernel(
    const unsigned short* __restrict__ Qs, const unsigned short* __restrict__ Ks,
    const unsigned short* __restrict__ VT, float* __restrict__ out) {
  constexpr int KVB = 32;
  __shared__ unsigned char ldsK[2][KVB * AA * 2];   // 2 x 32KB, XOR-swizzled rows
  __shared__ unsigned char ldsV[2][AA * KVB * 2];   // 2 x 32KB, pair-layout swizzled
  __shared__ unsigned char ldsP[8][16 * 80];        // per-wave P bounce, 10KB

  const int tid = threadIdx.x, lane = tid & 63, wave = tid >> 6;
  const int L = blockIdx.x;
  const int b = L & 31;                      // XCD = L%8 = b%8
  const int fi = L >> 5;                     // fold index 0..7 (i=0 = most work, first)
  const int chunk = (wave < 4) ? (15 - fi) : fi;   // late chunk for waves 0-3
  const int q0w = chunk * 64 + (wave & 3) * 16;

  const int ntiles = 2 * (16 - fi);          // block loop bound (late chunk's range)
  const int myN = (wave < 4) ? ntiles : 2 * (fi + 1);  // this wave's compute bound

  // hoisted per-lane stage offsets (elements); 4096 chunks over 512 threads
  const unsigned short* kbase = Ks + (size_t)b * SS * AA;
  const unsigned short* vbase = VT + (size_t)b * AA * SS;
  unsigned int koff[4], voff[4];
  #pragma unroll
  for (int i = 0; i < 4; ++i) {
    int c = i * 512 + tid;                   // 2048 chunks
    int r = c >> 6;                          // K row 0..31
    int cb = ((c & 63) * 16) ^ ((r & 7) << 4);
    koff[i] = r * AA + (cb >> 1);
    int pair = c >> 3;
    int within = (c & 7) * 16;
    int half = within >> 6;
    int kb = (within & 63) ^ ((pair & 3) << 4);
    int a_ = pair * 2 + half;
    voff[i] = a_ * SS + (kb >> 1);
  }

  // Q fragments in registers: 16 rows x 512 k
  s16x8 qf[16];
  {
    int qrow = q0w + (lane & 15);
    int qr = qrow < SS ? qrow : SS - 1;
    const unsigned short* qp = Qs + (size_t)(b * SS + qr) * AA + (lane >> 4) * 8;
    #pragma unroll
    for (int f = 0; f < 16; ++f) qf[f] = *(const s16x8*)(qp + f * 32);
  }

  f32x4 o[32];
  #pragma unroll
  for (int n = 0; n < 32; ++n) o[n] = f32x4{0.f, 0.f, 0.f, 0.f};
  float mrun[4], ps[4];
  #pragma unroll
  for (int j = 0; j < 4; ++j) { mrun[j] = -__builtin_inff(); ps[j] = 0.f; }

  auto stageKV = [&](int buf, int t) {
    #pragma unroll
    for (int i = 0; i < 4; ++i)
      gl_lds16(kbase + koff[i] + (unsigned)(t * (KVB * AA)),
               &ldsK[buf][(i * 512 + tid) * 16]);
    #pragma unroll
    for (int i = 0; i < 4; ++i)
      gl_lds16(vbase + voff[i] + (unsigned)(t * KVB),
               &ldsV[buf][(i * 512 + tid) * 16]);
  };

  stageKV(0, 0);
  asm volatile("s_waitcnt vmcnt(0)" ::: "memory");
  wg_barrier();

  for (int t = 0; t < ntiles; ++t) {
    const int cur = t & 1;
    const int k0 = t * KVB;
    if (t + 1 < ntiles) stageKV(cur ^ 1, t + 1);   // issue prefetch BEFORE compute (all waves)

    if (t < myN) {  // wave-uniform branch: early waves skip compute past their range
      // ---- QK^T: p[16 rows x 32 keys], 4 independent 8-deep MFMA chains ----
      f32x4 p0a = {0.f, 0.f, 0.f, 0.f}, p0b = {0.f, 0.f, 0.f, 0.f};
      f32x4 p1a = {0.f, 0.f, 0.f, 0.f}, p1b = {0.f, 0.f, 0.f, 0.f};
      {
        const int r0 = lane & 15;
        const int sw = (r0 & 7) << 4;
        const int kb16 = (lane >> 4) * 16;
        const int rb0 = r0 << 10, rb1 = (r0 + 16) << 10;
        #pragma unroll
        for (int f = 0; f < 8; ++f) {
          const int offA = f * 64 + kb16;
          const int offB = (f + 8) * 64 + kb16;
          s16x8 k0A = *(const s16x8*)&ldsK[cur][rb0 + (offA ^ sw)];
          s16x8 k1A = *(const s16x8*)&ldsK[cur][rb1 + (offA ^ sw)];
          s16x8 k0B = *(const s16x8*)&ldsK[cur][rb0 + (offB ^ sw)];
          s16x8 k1B = *(const s16x8*)&ldsK[cur][rb1 + (offB ^ sw)];
          p0a = __builtin_amdgcn_mfma_f32_16x16x32_bf16(qf[f], k0A, p0a, 0, 0, 0);
          p1a = __builtin_amdgcn_mfma_f32_16x16x32_bf16(qf[f], k1A, p1a, 0, 0, 0);
          p0b = __builtin_amdgcn_mfma_f32_16x16x32_bf16(qf[f + 8], k0B, p0b, 0, 0, 0);
          p1b = __builtin_amdgcn_mfma_f32_16x16x32_bf16(qf[f + 8], k1B, p1b, 0, 0, 0);
        }
      }
      f32x4 p0 = p0a + p0b, p1 = p1a + p1b;

      // ---- causal mask + defer-max online softmax ----
      const int kcol = k0 + (lane & 15);
      float lm[4];
      #pragma unroll
      for (int j = 0; j < 4; ++j) {
        const int q = q0w + (lane >> 4) * 4 + j;
        float s0 = p0[j], s1 = p1[j];
        if (kcol > q || kcol >= SS) s0 = -__builtin_inff();
        if (kcol + 16 > q || kcol + 16 >= SS) s1 = -__builtin_inff();
        p0[j] = s0; p1[j] = s1;
        lm[j] = fmaxf(s0, s1);
      }
      const int myneed = (lm[0] > mrun[0] + 8.f) | (lm[1] > mrun[1] + 8.f) |
                         (lm[2] > mrun[2] + 8.f) | (lm[3] > mrun[3] + 8.f);
      if (__any(myneed)) {                        // rare after tile 0
        float rm[4] = {lm[0], lm[1], lm[2], lm[3]};
        #pragma unroll
        for (int st = 1; st <= 8; st <<= 1)
          #pragma unroll
          for (int j = 0; j < 4; ++j) rm[j] = fmaxf(rm[j], __shfl_xor(rm[j], st));
        float corr[4];
        #pragma unroll
        for (int j = 0; j < 4; ++j) {
          const float mnew = fmaxf(mrun[j], rm[j]);
          corr[j] = fast_exp2(mrun[j] - mnew);    // exp2(-inf)=0 on first tile
          mrun[j] = mnew;
          ps[j] *= corr[j];
        }
        #pragma unroll
        for (int n = 0; n < 32; ++n)
          #pragma unroll
          for (int j = 0; j < 4; ++j) o[n][j] *= corr[j];
      }
      #pragma unroll
      for (int j = 0; j < 4; ++j) {               // P = exp2(s - m); per-lane partial sums
        const float e0 = fast_exp2(p0[j] - mrun[j]);
        const float e1 = fast_exp2(p1[j] - mrun[j]);
        ps[j] += e0 + e1;
        p0[j] = e0; p1[j] = e1;
      }

      // ---- P (C-layout) -> bf16 -> wave-private LDS -> A-fragment ----
      {
        unsigned short* pb = (unsigned short*)&ldsP[wave][0];
        const int prow = (lane >> 4) * 4, pc = lane & 15;
        #pragma unroll
        for (int j = 0; j < 4; ++j) {
          pb[(prow + j) * 40 + pc]      = f2bf(p0[j]);
          pb[(prow + j) * 40 + pc + 16] = f2bf(p1[j]);
        }
      }
      s16x8 pa;
      {
        const unsigned char* pp = &ldsP[wave][(lane & 15) * 80 + (lane >> 4) * 16];
        s16x4 lo = *(const s16x4*)pp;
        s16x4 hi = *(const s16x4*)(pp + 8);
        pa = s16x8{lo[0], lo[1], lo[2], lo[3], hi[0], hi[1], hi[2], hi[3]};
      }

      // ---- PV: o[q][a] += P[q][k] * VT[a][k] ----
      #pragma unroll
      for (int n = 0; n < 32; ++n) {
        const int a_ = n * 16 + (lane & 15);
        const int pair = a_ >> 1;
        const int off = pair * 128 + (a_ & 1) * 64 + (((lane >> 4) * 16) ^ ((pair & 3) << 4));
        s16x8 vb = *(const s16x8*)&ldsV[cur][off];
        o[n] = __builtin_amdgcn_mfma_f32_16x16x32_bf16(pa, vb, o[n], 0, 0, 0);
      }
    }

    asm volatile("s_waitcnt vmcnt(0)" ::: "memory");  // prefetch landed (covered by compute)
    wg_barrier();                                     // tile cur fully consumed by all waves
  }

  // ---- finalize: reduce per-lane partial sums, divide, store fp32 ----
  #pragma unroll
  for (int st = 1; st <= 8; st <<= 1)
    #pragma unroll
    for (int j = 0; j < 4; ++j) ps[j] += __shfl_xor(ps[j], st);
  #pragma unroll
  for (int j = 0; j < 4; ++j) {
    const int q = q0w + (lane >> 4) * 4 + j;
    if (q < SS) {
      const float inv = 1.0f / ps[j];
      float* op = out + (size_t)(b * SS + q) * AA + (lane & 15);
      #pragma unroll
      for (int n = 0; n < 32; ++n) op[n * 16] = o[n][j] * inv;
    }
  }
}

// ---------------------------------------------------------------- launch
extern "C" void kernel_launch(void* const* d_in, const int* in_sizes, int n_in,
                              void* d_out, int out_size, void* d_ws, size_t ws_size,
                              hipStream_t stream) {
  const float* x  = (const float*)d_in[0];
  const float* Wk = (const float*)d_in[1];
  const float* bk = (const float*)d_in[2];
  const float* Wq = (const float*)d_in[3];
  const float* bq = (const float*)d_in[4];
  const float* Wv = (const float*)d_in[5];
  const float* bv = (const float*)d_in[6];

  char* ws = (char*)d_ws;
  unsigned short* X16 = (unsigned short*)(ws + OFF_X16);
  unsigned short* Qw  = (unsigned short*)(ws + OFF_Q);
  unsigned short* Kw  = (unsigned short*)(ws + OFF_K);
  unsigned short* VTw = (unsigned short*)(ws + OFF_VT);
  unsigned short* WT  = (unsigned short*)(ws + OFF_WT);

  x_to_bf16_kernel<<<dim3(2048), dim3(256), 0, stream>>>(x, X16);
  wt_kernel<<<dim3(EE / 64, AA / 64, 3), dim3(256), 0, stream>>>(Wq, Wk, Wv, WT);
  proj_kernel<<<dim3(3000), dim3(256), 0, stream>>>(
      X16, WT, bq, bk, bv, Qw, Kw, VTw);
  attn_kernel<<<dim3(256), dim3(512), 0, stream>>>(Qw, Kw, VTw, (float*)d_out);
}

// Round 18
// 301.114 us; speedup vs baseline: 1.2700x; 1.0178x over previous
//
#include <hip/hip_runtime.h>
#include <hip/hip_bf16.h>
#include <stdint.h>

#define DEVI __device__ __forceinline__

typedef short s16x8 __attribute__((ext_vector_type(8)));
typedef short s16x4 __attribute__((ext_vector_type(4)));
typedef float f32x4 __attribute__((ext_vector_type(4)));

static constexpr int BB = 32, SS = 1000, EE = 1024, AA = 512;
static constexpr int MM = BB * SS;  // 32000

// workspace layout (bytes)
static constexpr size_t OFF_X16 = 0;                                   // [M][E] bf16 (dead after proj -> reused for attn partials)
static constexpr size_t OFF_Q   = OFF_X16 + (size_t)MM * EE * 2;       // [M][A] bf16 (pre-scaled by log2e/sqrt(S))
static constexpr size_t OFF_K   = OFF_Q  + (size_t)MM * AA * 2;        // [M][A] bf16
static constexpr size_t OFF_VT  = OFF_K  + (size_t)MM * AA * 2;       // [B][A][S] bf16
static constexpr size_t OFF_WT  = OFF_VT + (size_t)BB * AA * SS * 2;   // 3 x [A][E] bf16 (z=0:Wq 1:Wk 2:Wv)

// attn K-split partials (inside X16 region): chunks 5..7 (q rows 640..1023), 2 slots
static constexpr int PROWS = BB * 3 * 128;                 // 12288 rows per slot
static constexpr size_t ML_OFF = (size_t)2 * PROWS * 512;  // floats; after the two o-slabs

DEVI unsigned short f2bf(float f) {  // round-to-nearest-even f32 -> bf16
  union { float f; unsigned int u; } c; c.f = f;
  unsigned int u = c.u + 0x7fffu + ((c.u >> 16) & 1u);
  return (unsigned short)(u >> 16);
}

DEVI void gl_lds16(const void* g, void* l) {  // async global->LDS, 16B/lane, linear dest
  __builtin_amdgcn_global_load_lds(
      (const __attribute__((address_space(1))) unsigned int*)g,
      (__attribute__((address_space(3))) unsigned int*)l, 16, 0, 0);
}

DEVI void wg_barrier() {
  asm volatile("" ::: "memory");
  __builtin_amdgcn_s_barrier();
  asm volatile("" ::: "memory");
}

DEVI float fast_exp2(float x) {
#if __has_builtin(__builtin_amdgcn_exp2f)
  return __builtin_amdgcn_exp2f(x);
#else
  return __builtin_exp2f(x);
#endif
}

// ---------------------------------------------------------------- prep kernels
__global__ __launch_bounds__(256) void x_to_bf16_kernel(const float* __restrict__ x,
                                                        unsigned short* __restrict__ x16) {
  const long n4 = (long)MM * EE / 4;
  long i = (long)blockIdx.x * blockDim.x + threadIdx.x;
  const long stride = (long)gridDim.x * blockDim.x;
  for (; i < n4; i += stride) {
    const float4 v = ((const float4*)x)[i];
    ushort4 o;
    o.x = f2bf(v.x); o.y = f2bf(v.y); o.z = f2bf(v.z); o.w = f2bf(v.w);
    ((ushort4*)x16)[i] = o;
  }
}

// transpose+convert W [E][A] f32 -> WT [A][E] bf16; grid (E/64, A/64, 3)
__global__ __launch_bounds__(256) void wt_kernel(const float* __restrict__ Wq,
                                                 const float* __restrict__ Wk,
                                                 const float* __restrict__ Wv,
                                                 unsigned short* __restrict__ WT) {
  const float* W = (blockIdx.z == 0) ? Wq : (blockIdx.z == 1) ? Wk : Wv;
  unsigned short* out = WT + (size_t)blockIdx.z * AA * EE;
  __shared__ unsigned short t[64][65];
  const int k0 = blockIdx.x * 64, n0 = blockIdx.y * 64;
  #pragma unroll
  for (int i = 0; i < 16; ++i) {
    int idx = i * 256 + threadIdx.x;
    int r = idx >> 6, c = idx & 63;              // r: k-local, c: n-local
    t[r][c] = f2bf(W[(size_t)(k0 + r) * AA + n0 + c]);
  }
  __syncthreads();
  #pragma unroll
  for (int i = 0; i < 16; ++i) {
    int idx = i * 256 + threadIdx.x;
    int r = idx >> 6, c = idx & 63;              // r: n-local, c: k-local
    out[(size_t)(n0 + r) * EE + k0 + c] = t[c][r];
  }
}

// ---------------------------------------------------------------- QKV projection
// (unchanged from R16 baseline: 128x128 tile, BK=64, dbuf gl_lds + vmcnt(8),
// 1D grid 3000 with (n,z) innermost for X-panel L2/L3 reuse)
__global__ __launch_bounds__(256, 2) void proj_kernel(
    const unsigned short* __restrict__ X16, const unsigned short* __restrict__ WT,
    const float* __restrict__ bq, const float* __restrict__ bk, const float* __restrict__ bv,
    unsigned short* __restrict__ Qo, unsigned short* __restrict__ Ko,
    unsigned short* __restrict__ VTo) {
  constexpr int BK = 64, NKT = EE / BK;  // 16 K-steps
  __shared__ unsigned char lds[65536];   // 2x16KB A | 2x16KB B; reused by epilogue
  unsigned char* ldsA = lds;             // [buf][128 rows][128B]
  unsigned char* ldsB = lds + 32768;
  const int tid = threadIdx.x, lane = tid & 63, wave = tid >> 6;
  const int id = blockIdx.x;
  const int r12 = id % 12;
  const int z = r12 >> 2;                 // 0:Wq 1:Wk 2:Wv
  const int m0 = (id / 12) * 128, n0 = (r12 & 3) * 128;
  const unsigned short* Wz = WT + (size_t)z * AA * EE;

  f32x4 acc[4][4];
  #pragma unroll
  for (int i = 0; i < 4; ++i)
    #pragma unroll
    for (int j = 0; j < 4; ++j) acc[i][j] = f32x4{0.f, 0.f, 0.f, 0.f};

  auto stage = [&](int buf, int kt) {
    #pragma unroll
    for (int i = 0; i < 4; ++i) {
      int c = i * 256 + tid;                 // 1024 16B chunks (A-tile)
      int row = c >> 3;
      int cb = ((c & 7) * 16) ^ ((row & 7) << 4);   // pre-swizzled source column
      gl_lds16(X16 + (size_t)(m0 + row) * EE + kt * BK + (cb >> 1), ldsA + buf * 16384 + c * 16);
    }
    #pragma unroll
    for (int i = 0; i < 4; ++i) {
      int c = i * 256 + tid;
      int row = c >> 3;
      int cb = ((c & 7) * 16) ^ ((row & 7) << 4);
      gl_lds16(Wz + (size_t)(n0 + row) * EE + kt * BK + (cb >> 1), ldsB + buf * 16384 + c * 16);
    }
  };

  auto compute = [&](int buf) {
    #pragma unroll
    for (int kk = 0; kk < 2; ++kk) {
      s16x8 a[4], b[4];
      #pragma unroll
      for (int m = 0; m < 4; ++m) {
        int row = (wave >> 1) * 64 + m * 16 + (lane & 15);
        int cb = (kk * 64 + (lane >> 4) * 16) ^ ((row & 7) << 4);
        a[m] = *(const s16x8*)(ldsA + buf * 16384 + row * 128 + cb);
      }
      #pragma unroll
      for (int n = 0; n < 4; ++n) {
        int row = (wave & 1) * 64 + n * 16 + (lane & 15);
        int cb = (kk * 64 + (lane >> 4) * 16) ^ ((row & 7) << 4);
        b[n] = *(const s16x8*)(ldsB + buf * 16384 + row * 128 + cb);
      }
      #pragma unroll
      for (int m = 0; m < 4; ++m)
        #pragma unroll
        for (int n = 0; n < 4; ++n)
          acc[m][n] = __builtin_amdgcn_mfma_f32_16x16x32_bf16(a[m], b[n], acc[m][n], 0, 0, 0);
    }
  };

  stage(0, 0);
  for (int kt = 0; kt < NKT; ++kt) {
    const int cur = kt & 1;
    if (kt + 1 < NKT) {
      stage(cur ^ 1, kt + 1);
      asm volatile("s_waitcnt vmcnt(8)" ::: "memory");  // current tile done; prefetch stays in flight
    } else {
      asm volatile("s_waitcnt vmcnt(0)" ::: "memory");
    }
    wg_barrier();
    compute(cur);
    wg_barrier();
  }

  // ---- epilogue: bias (+scale for Q), bf16, coalesce via LDS [128][136] tile ----
  const float* bias = (z == 0) ? bq : (z == 1) ? bk : bv;
  const float scale = (z == 0) ? 0.04562280215f : 1.0f;  // log2(e)/sqrt(1000) folded into Q
  unsigned short* T = (unsigned short*)lds;              // 128*136*2 = 34816B
  const int rbase = (wave >> 1) * 64 + (lane >> 4) * 4;  // local row (m / s dim)
  const int cbase = (wave & 1) * 64 + (lane & 15);       // local col (n / a dim)
  float bvals[4];
  #pragma unroll
  for (int n = 0; n < 4; ++n) bvals[n] = bias[n0 + cbase + n * 16];
  #pragma unroll
  for (int m = 0; m < 4; ++m) {
    #pragma unroll
    for (int n = 0; n < 4; ++n) {
      const int cl = cbase + n * 16;
      #pragma unroll
      for (int j = 0; j < 4; ++j) {
        const int rl = rbase + m * 16 + j;
        const unsigned short h = f2bf((acc[m][n][j] + bvals[n]) * scale);
        if (z == 2) T[cl * 136 + rl] = h;   // transposed: [a_local][s_local]
        else        T[rl * 136 + cl] = h;   // natural:    [s_local][a_local]
      }
    }
  }
  wg_barrier();
  #pragma unroll
  for (int i = 0; i < 8; ++i) {
    int c2 = i * 256 + tid;                 // 2048 chunks of 16B
    int r = c2 >> 4, ch = (c2 & 15) * 8;
    s16x8 chunk = *(const s16x8*)&T[r * 136 + ch];
    if (z == 2) {
      // r = a_local, ch.. = s_local. 16B chunk never straddles a batch (8 | 1000).
      const int rowg0 = m0 + ch;
      const int bb2 = rowg0 / SS, ss2 = rowg0 - bb2 * SS;
      *(s16x8*)&VTo[(size_t)bb2 * AA * SS + (size_t)(n0 + r) * SS + ss2] = chunk;
    } else {
      unsigned short* O = (z == 0) ? Qo : Ko;
      *(s16x8*)&O[(size_t)(m0 + r) * AA + n0 + ch] = chunk;
    }
  }
}

// ---------------------------------------------------------------- fused causal attention
// K-SPLIT balance (T=20): grid 256, b=L&31 (XCD pin), g=7-(L>>5) (long first).
// Phase1: own 128-row chunk g, k-tiles [0, min(4(g+1),20)); g<=4 complete (final
// store), g>=5 partial -> slot A. Phase2 (g<=2): partner r=7-g, its k-tail
// [20, 4(r+1)) -> partial slot B. Register state reused sequentially (no R7 spill).
// Loop totals {16,16,16,16,20,20,20,20} vs old makespan 32. Partials in dead X16 ws.
// K+V double-buffered (138KB LDS, 1 block/CU, 8 waves): stage(t+1) BEFORE compute(t).
__global__ __launch_bounds__(512, 2) void attn_kernel(
    const unsigned short* __restrict__ Qs, const unsigned short* __restrict__ Ks,
    const unsigned short* __restrict__ VT, float* __restrict__ out,
    float* __restrict__ part) {
  constexpr int KVB = 32;
  __shared__ unsigned char ldsK[2][KVB * AA * 2];   // 2 x 32KB, XOR-swizzled rows
  __shared__ unsigned char ldsV[2][AA * KVB * 2];   // 2 x 32KB, pair-layout swizzled
  __shared__ unsigned char ldsP[8][16 * 80];        // per-wave P bounce, 10KB

  const int tid = threadIdx.x, lane = tid & 63, wave = tid >> 6;
  const int L = blockIdx.x;
  const int b = L & 31;                      // XCD = L%8 = b%8
  const int g = 7 - (L >> 5);                // own chunk; g=7 (20 iters) dispatches first

  // hoisted per-lane stage offsets (elements); 4096 chunks over 512 threads
  const unsigned short* kbase = Ks + (size_t)b * SS * AA;
  const unsigned short* vbase = VT + (size_t)b * AA * SS;
  unsigned int koff[4], voff[4];
  #pragma unroll
  for (int i = 0; i < 4; ++i) {
    int c = i * 512 + tid;                   // 2048 chunks
    int r = c >> 6;                          // K row 0..31
    int cb = ((c & 63) * 16) ^ ((r & 7) << 4);
    koff[i] = r * AA + (cb >> 1);
    int pair = c >> 3;
    int within = (c & 7) * 16;
    int half = within >> 6;
    int kb = (within & 63) ^ ((pair & 3) << 4);
    int a_ = pair * 2 + half;
    voff[i] = a_ * SS + (kb >> 1);
  }

  auto stageKV = [&](int buf, int t) {
    #pragma unroll
    for (int i = 0; i < 4; ++i)
      gl_lds16(kbase + koff[i] + (unsigned)(t * (KVB * AA)),
               &ldsK[buf][(i * 512 + tid) * 16]);
    #pragma unroll
    for (int i = 0; i < 4; ++i)
      gl_lds16(vbase + voff[i] + (unsigned)(t * KVB),
               &ldsV[buf][(i * 512 + tid) * 16]);
  };

  // phase descriptors: {rowbase, t0, t1, mode(0 final,1 slotA,2 slotB), chunkidx}
  int ownN = 4 * (g + 1);
  int rb_[2], t0_[2], t1_[2], md_[2], cx_[2];
  int nph = 1;
  rb_[0] = 128 * g; t0_[0] = 0; t1_[0] = (ownN < 20) ? ownN : 20;
  md_[0] = (g <= 4) ? 0 : 1; cx_[0] = g - 5;
  if (g <= 2) {
    int r = 7 - g;
    rb_[1] = 128 * r; t0_[1] = 20; t1_[1] = 4 * (r + 1); md_[1] = 2; cx_[1] = r - 5;
    nph = 2;
  }

  for (int ph = 0; ph < nph; ++ph) {
    const int rowbase = rb_[ph], tbeg = t0_[ph], tend = t1_[ph];
    const int mode = md_[ph], cidx = cx_[ph];
    const int q0w = rowbase + wave * 16;

    // Q fragments for this phase's rows
    s16x8 qf[16];
    {
      int qrow = q0w + (lane & 15);
      int qr = qrow < SS ? qrow : SS - 1;
      const unsigned short* qp = Qs + (size_t)(b * SS + qr) * AA + (lane >> 4) * 8;
      #pragma unroll
      for (int f = 0; f < 16; ++f) qf[f] = *(const s16x8*)(qp + f * 32);
    }

    f32x4 o[32];
    #pragma unroll
    for (int n = 0; n < 32; ++n) o[n] = f32x4{0.f, 0.f, 0.f, 0.f};
    float mrun[4], ps[4];
    #pragma unroll
    for (int j = 0; j < 4; ++j) { mrun[j] = -__builtin_inff(); ps[j] = 0.f; }

    stageKV(0, tbeg);
    asm volatile("s_waitcnt vmcnt(0)" ::: "memory");
    wg_barrier();

    for (int t = tbeg; t < tend; ++t) {
      const int cur = (t - tbeg) & 1;
      const int k0 = t * KVB;
      if (t + 1 < tend) stageKV(cur ^ 1, t + 1);   // prefetch BEFORE compute

      // ---- QK^T: 4 independent 8-deep MFMA chains ----
      f32x4 p0a = {0.f, 0.f, 0.f, 0.f}, p0b = {0.f, 0.f, 0.f, 0.f};
      f32x4 p1a = {0.f, 0.f, 0.f, 0.f}, p1b = {0.f, 0.f, 0.f, 0.f};
      {
        const int r0 = lane & 15;
        const int sw = (r0 & 7) << 4;
        const int kb16 = (lane >> 4) * 16;
        const int rb0 = r0 << 10, rb1 = (r0 + 16) << 10;
        #pragma unroll
        for (int f = 0; f < 8; ++f) {
          const int offA = f * 64 + kb16;
          const int offB = (f + 8) * 64 + kb16;
          s16x8 k0A = *(const s16x8*)&ldsK[cur][rb0 + (offA ^ sw)];
          s16x8 k1A = *(const s16x8*)&ldsK[cur][rb1 + (offA ^ sw)];
          s16x8 k0B = *(const s16x8*)&ldsK[cur][rb0 + (offB ^ sw)];
          s16x8 k1B = *(const s16x8*)&ldsK[cur][rb1 + (offB ^ sw)];
          p0a = __builtin_amdgcn_mfma_f32_16x16x32_bf16(qf[f], k0A, p0a, 0, 0, 0);
          p1a = __builtin_amdgcn_mfma_f32_16x16x32_bf16(qf[f], k1A, p1a, 0, 0, 0);
          p0b = __builtin_amdgcn_mfma_f32_16x16x32_bf16(qf[f + 8], k0B, p0b, 0, 0, 0);
          p1b = __builtin_amdgcn_mfma_f32_16x16x32_bf16(qf[f + 8], k1B, p1b, 0, 0, 0);
        }
      }
      f32x4 p0 = p0a + p0b, p1 = p1a + p1b;

      // ---- causal mask + defer-max online softmax ----
      const int kcol = k0 + (lane & 15);
      float lm[4];
      #pragma unroll
      for (int j = 0; j < 4; ++j) {
        const int q = q0w + (lane >> 4) * 4 + j;
        float s0 = p0[j], s1 = p1[j];
        if (kcol > q || kcol >= SS) s0 = -__builtin_inff();
        if (kcol + 16 > q || kcol + 16 >= SS) s1 = -__builtin_inff();
        p0[j] = s0; p1[j] = s1;
        lm[j] = fmaxf(s0, s1);
      }
      const int myneed = (lm[0] > mrun[0] + 8.f) | (lm[1] > mrun[1] + 8.f) |
                         (lm[2] > mrun[2] + 8.f) | (lm[3] > mrun[3] + 8.f);
      if (__any(myneed)) {
        float rm[4] = {lm[0], lm[1], lm[2], lm[3]};
        #pragma unroll
        for (int st = 1; st <= 8; st <<= 1)
          #pragma unroll
          for (int j = 0; j < 4; ++j) rm[j] = fmaxf(rm[j], __shfl_xor(rm[j], st));
        float corr[4];
        #pragma unroll
        for (int j = 0; j < 4; ++j) {
          const float mnew = fmaxf(mrun[j], rm[j]);
          corr[j] = fast_exp2(mrun[j] - mnew);    // exp2(-inf)=0 on first tile
          mrun[j] = mnew;
          ps[j] *= corr[j];
        }
        #pragma unroll
        for (int n = 0; n < 32; ++n)
          #pragma unroll
          for (int j = 0; j < 4; ++j) o[n][j] *= corr[j];
      }
      #pragma unroll
      for (int j = 0; j < 4; ++j) {
        const float e0 = fast_exp2(p0[j] - mrun[j]);
        const float e1 = fast_exp2(p1[j] - mrun[j]);
        ps[j] += e0 + e1;
        p0[j] = e0; p1[j] = e1;
      }

      // ---- P -> bf16 -> wave-private LDS -> A-fragment ----
      {
        unsigned short* pb = (unsigned short*)&ldsP[wave][0];
        const int prow = (lane >> 4) * 4, pc = lane & 15;
        #pragma unroll
        for (int j = 0; j < 4; ++j) {
          pb[(prow + j) * 40 + pc]      = f2bf(p0[j]);
          pb[(prow + j) * 40 + pc + 16] = f2bf(p1[j]);
        }
      }
      s16x8 pa;
      {
        const unsigned char* pp = &ldsP[wave][(lane & 15) * 80 + (lane >> 4) * 16];
        s16x4 lo = *(const s16x4*)pp;
        s16x4 hi = *(const s16x4*)(pp + 8);
        pa = s16x8{lo[0], lo[1], lo[2], lo[3], hi[0], hi[1], hi[2], hi[3]};
      }

      // ---- PV ----
      #pragma unroll
      for (int n = 0; n < 32; ++n) {
        const int a_ = n * 16 + (lane & 15);
        const int pair = a_ >> 1;
        const int off = pair * 128 + (a_ & 1) * 64 + (((lane >> 4) * 16) ^ ((pair & 3) << 4));
        s16x8 vb = *(const s16x8*)&ldsV[cur][off];
        o[n] = __builtin_amdgcn_mfma_f32_16x16x32_bf16(pa, vb, o[n], 0, 0, 0);
      }

      asm volatile("s_waitcnt vmcnt(0)" ::: "memory");  // prefetch landed (covered by compute)
      wg_barrier();
    }

    // ---- finalize phase: reduce l; final store or partial store ----
    #pragma unroll
    for (int st = 1; st <= 8; st <<= 1)
      #pragma unroll
      for (int j = 0; j < 4; ++j) ps[j] += __shfl_xor(ps[j], st);

    if (mode == 0) {
      #pragma unroll
      for (int j = 0; j < 4; ++j) {
        const int q = q0w + (lane >> 4) * 4 + j;
        if (q < SS) {
          const float inv = 1.0f / ps[j];
          float* op = out + (size_t)(b * SS + q) * AA + (lane & 15);
          #pragma unroll
          for (int n = 0; n < 32; ++n) op[n * 16] = o[n][j] * inv;
        }
      }
    } else {
      const int slot = mode - 1;
      #pragma unroll
      for (int j = 0; j < 4; ++j) {
        const int rl = wave * 16 + (lane >> 4) * 4 + j;       // row within chunk
        const size_t idx = (size_t)slot * PROWS + ((size_t)(b * 3 + cidx) * 128 + rl);
        float* po = part + idx * 512 + (lane & 15);
        #pragma unroll
        for (int n = 0; n < 32; ++n) po[n * 16] = o[n][j];    // raw (unnormalized)
        if ((lane & 15) == 0) {
          float* pml = part + ML_OFF + idx * 2;
          pml[0] = mrun[j];
          pml[1] = ps[j];
        }
      }
    }
  }
}

// ---------------------------------------------------------------- combine partials
// rows 640..999 of each batch (chunks 5..7): merge slot A (k head) + slot B (k tail).
__global__ __launch_bounds__(256) void combine_kernel(const float* __restrict__ part,
                                                      float* __restrict__ out) {
  const int rid = blockIdx.x * 2 + (threadIdx.x >> 7);   // 0..12287
  const int t = threadIdx.x & 127;                       // float4 col index
  const int b = rid / 384;
  const int rem = rid - b * 384;
  const int c = rem >> 7, row = rem & 127;
  const int q = (c + 5) * 128 + row;
  if (q >= SS) return;
  const float* mlA = part + ML_OFF + (size_t)rid * 2;
  const float* mlB = part + ML_OFF + ((size_t)PROWS + rid) * 2;
  const float mA = mlA[0], lA = mlA[1];
  const float mB = mlB[0], lB = mlB[1];
  const float m = fmaxf(mA, mB);
  const float sA = fast_exp2(mA - m), sB = fast_exp2(mB - m);
  const float inv = 1.0f / (lA * sA + lB * sB);
  const float4 a = ((const float4*)(part + (size_t)rid * 512))[t];
  const float4 d = ((const float4*)(part + ((size_t)PROWS + rid) * 512))[t];
  float4 r;
  r.x = (a.x * sA + d.x * sB) * inv;
  r.y = (a.y * sA + d.y * sB) * inv;
  r.z = (a.z * sA + d.z * sB) * inv;
  r.w = (a.w * sA + d.w * sB) * inv;
  ((float4*)(out + ((size_t)b * SS + q) * AA))[t] = r;
}

// ---------------------------------------------------------------- launch
extern "C" void kernel_launch(void* const* d_in, const int* in_sizes, int n_in,
                              void* d_out, int out_size, void* d_ws, size_t ws_size,
                              hipStream_t stream) {
  const float* x  = (const float*)d_in[0];
  const float* Wk = (const float*)d_in[1];
  const float* bk = (const float*)d_in[2];
  const float* Wq = (const float*)d_in[3];
  const float* bq = (const float*)d_in[4];
  const float* Wv = (const float*)d_in[5];
  const float* bv = (const float*)d_in[6];

  char* ws = (char*)d_ws;
  unsigned short* X16 = (unsigned short*)(ws + OFF_X16);
  unsigned short* Qw  = (unsigned short*)(ws + OFF_Q);
  unsigned short* Kw  = (unsigned short*)(ws + OFF_K);
  unsigned short* VTw = (unsigned short*)(ws + OFF_VT);
  unsigned short* WT  = (unsigned short*)(ws + OFF_WT);
  float* Part = (float*)(ws + OFF_X16);   // X16 region dead after proj

  x_to_bf16_kernel<<<dim3(2048), dim3(256), 0, stream>>>(x, X16);
  wt_kernel<<<dim3(EE / 64, AA / 64, 3), dim3(256), 0, stream>>>(Wq, Wk, Wv, WT);
  proj_kernel<<<dim3(3000), dim3(256), 0, stream>>>(
      X16, WT, bq, bk, bv, Qw, Kw, VTw);
  attn_kernel<<<dim3(256), dim3(512), 0, stream>>>(Qw, Kw, VTw, (float*)d_out, Part);
  combine_kernel<<<dim3(PROWS / 2), dim3(256), 0, stream>>>(Part, (float*)d_out);
}

// Round 19
// 294.815 us; speedup vs baseline: 1.2971x; 1.0214x over previous
//
#include <hip/hip_runtime.h>
#include <hip/hip_bf16.h>
#include <stdint.h>

#define DEVI __device__ __forceinline__

typedef short s16x8 __attribute__((ext_vector_type(8)));
typedef short s16x4 __attribute__((ext_vector_type(4)));
typedef float f32x4 __attribute__((ext_vector_type(4)));

static constexpr int BB = 32, SS = 1000, EE = 1024, AA = 512;
static constexpr int MM = BB * SS;  // 32000

// workspace layout (bytes)
static constexpr size_t OFF_X16 = 0;                                   // [M][E] bf16 (dead after proj -> reused for attn partials)
static constexpr size_t OFF_Q   = OFF_X16 + (size_t)MM * EE * 2;       // [M][A] bf16 (pre-scaled by log2e/sqrt(S))
static constexpr size_t OFF_K   = OFF_Q  + (size_t)MM * AA * 2;        // [M][A] bf16
static constexpr size_t OFF_VT  = OFF_K  + (size_t)MM * AA * 2;       // [B][A][S] bf16
static constexpr size_t OFF_WT  = OFF_VT + (size_t)BB * AA * SS * 2;   // 3 x [A][E] bf16 (z=0:Wq 1:Wk 2:Wv)

// attn K-split partials (inside X16 region): chunks 5..7 (q rows 640..1023), 2 slots
static constexpr int PROWS = BB * 3 * 128;                 // 12288 rows per slot
static constexpr size_t ML_OFF = (size_t)2 * PROWS * 512;  // floats; after the two o-slabs

DEVI unsigned short f2bf(float f) {  // round-to-nearest-even f32 -> bf16
  union { float f; unsigned int u; } c; c.f = f;
  unsigned int u = c.u + 0x7fffu + ((c.u >> 16) & 1u);
  return (unsigned short)(u >> 16);
}

DEVI void gl_lds16(const void* g, void* l) {  // async global->LDS, 16B/lane, linear dest
  __builtin_amdgcn_global_load_lds(
      (const __attribute__((address_space(1))) unsigned int*)g,
      (__attribute__((address_space(3))) unsigned int*)l, 16, 0, 0);
}

DEVI void wg_barrier() {
  asm volatile("" ::: "memory");
  __builtin_amdgcn_s_barrier();
  asm volatile("" ::: "memory");
}

DEVI float fast_exp2(float x) {
#if __has_builtin(__builtin_amdgcn_exp2f)
  return __builtin_amdgcn_exp2f(x);
#else
  return __builtin_exp2f(x);
#endif
}

// ---------------------------------------------------------------- prep kernels
__global__ __launch_bounds__(256) void x_to_bf16_kernel(const float* __restrict__ x,
                                                        unsigned short* __restrict__ x16) {
  const long n4 = (long)MM * EE / 4;
  long i = (long)blockIdx.x * blockDim.x + threadIdx.x;
  const long stride = (long)gridDim.x * blockDim.x;
  for (; i < n4; i += stride) {
    const float4 v = ((const float4*)x)[i];
    ushort4 o;
    o.x = f2bf(v.x); o.y = f2bf(v.y); o.z = f2bf(v.z); o.w = f2bf(v.w);
    ((ushort4*)x16)[i] = o;
  }
}

// transpose+convert W [E][A] f32 -> WT [A][E] bf16; grid (E/64, A/64, 3)
__global__ __launch_bounds__(256) void wt_kernel(const float* __restrict__ Wq,
                                                 const float* __restrict__ Wk,
                                                 const float* __restrict__ Wv,
                                                 unsigned short* __restrict__ WT) {
  const float* W = (blockIdx.z == 0) ? Wq : (blockIdx.z == 1) ? Wk : Wv;
  unsigned short* out = WT + (size_t)blockIdx.z * AA * EE;
  __shared__ unsigned short t[64][65];
  const int k0 = blockIdx.x * 64, n0 = blockIdx.y * 64;
  #pragma unroll
  for (int i = 0; i < 16; ++i) {
    int idx = i * 256 + threadIdx.x;
    int r = idx >> 6, c = idx & 63;              // r: k-local, c: n-local
    t[r][c] = f2bf(W[(size_t)(k0 + r) * AA + n0 + c]);
  }
  __syncthreads();
  #pragma unroll
  for (int i = 0; i < 16; ++i) {
    int idx = i * 256 + threadIdx.x;
    int r = idx >> 6, c = idx & 63;              // r: n-local, c: k-local
    out[(size_t)(n0 + r) * EE + k0 + c] = t[c][r];
  }
}

// ---------------------------------------------------------------- QKV projection
// 128x128 tile, BK=64, dbuf gl_lds + vmcnt(8) (2-barrier structure, unchanged).
// Grid 3000 1D with XCD-PANEL PINNING: 96 consecutive ids = 8 panels x 12 (n,z)
// blocks; decode keeps id === p (mod 8) for all 12 blocks of panel p -> same XCD
// (round-robin id->XCD) -> X panel fetched ONCE into that XCD's L2; WT (3MB)
// stays L2-resident per XCD. Per-XCD working set 3.25MB < 4MB.
__global__ __launch_bounds__(256, 2) void proj_kernel(
    const unsigned short* __restrict__ X16, const unsigned short* __restrict__ WT,
    const float* __restrict__ bq, const float* __restrict__ bk, const float* __restrict__ bv,
    unsigned short* __restrict__ Qo, unsigned short* __restrict__ Ko,
    unsigned short* __restrict__ VTo) {
  constexpr int BK = 64, NKT = EE / BK;  // 16 K-steps
  __shared__ unsigned char lds[65536];   // 2x16KB A | 2x16KB B; reused by epilogue
  unsigned char* ldsA = lds;             // [buf][128 rows][128B]
  unsigned char* ldsB = lds + 32768;
  const int tid = threadIdx.x, lane = tid & 63, wave = tid >> 6;
  const int phys = blockIdx.x;
  int p, r;
  if (phys < 2976) {                     // 31 full groups of 96 (8 panels x 12)
    const int gq = phys / 96, w = phys % 96;
    p = gq * 8 + (w & 7);                // panel; id%8 == p%8 -> XCD-pinned
    r = w >> 3;                          // 0..11 (n,z) combo
  } else {                               // tail: panels 248,249 (24 blocks)
    const int w = phys - 2976;
    p = 248 + (w & 1);
    r = w >> 1;
  }
  const int z = r >> 2;                  // 0:Wq 1:Wk 2:Wv
  const int m0 = p * 128, n0 = (r & 3) * 128;
  const unsigned short* Wz = WT + (size_t)z * AA * EE;

  f32x4 acc[4][4];
  #pragma unroll
  for (int i = 0; i < 4; ++i)
    #pragma unroll
    for (int j = 0; j < 4; ++j) acc[i][j] = f32x4{0.f, 0.f, 0.f, 0.f};

  auto stage = [&](int buf, int kt) {
    #pragma unroll
    for (int i = 0; i < 4; ++i) {
      int c = i * 256 + tid;                 // 1024 16B chunks (A-tile)
      int row = c >> 3;
      int cb = ((c & 7) * 16) ^ ((row & 7) << 4);   // pre-swizzled source column
      gl_lds16(X16 + (size_t)(m0 + row) * EE + kt * BK + (cb >> 1), ldsA + buf * 16384 + c * 16);
    }
    #pragma unroll
    for (int i = 0; i < 4; ++i) {
      int c = i * 256 + tid;
      int row = c >> 3;
      int cb = ((c & 7) * 16) ^ ((row & 7) << 4);
      gl_lds16(Wz + (size_t)(n0 + row) * EE + kt * BK + (cb >> 1), ldsB + buf * 16384 + c * 16);
    }
  };

  auto compute = [&](int buf) {
    #pragma unroll
    for (int kk = 0; kk < 2; ++kk) {
      s16x8 a[4], b[4];
      #pragma unroll
      for (int m = 0; m < 4; ++m) {
        int row = (wave >> 1) * 64 + m * 16 + (lane & 15);
        int cb = (kk * 64 + (lane >> 4) * 16) ^ ((row & 7) << 4);
        a[m] = *(const s16x8*)(ldsA + buf * 16384 + row * 128 + cb);
      }
      #pragma unroll
      for (int n = 0; n < 4; ++n) {
        int row = (wave & 1) * 64 + n * 16 + (lane & 15);
        int cb = (kk * 64 + (lane >> 4) * 16) ^ ((row & 7) << 4);
        b[n] = *(const s16x8*)(ldsB + buf * 16384 + row * 128 + cb);
      }
      #pragma unroll
      for (int m = 0; m < 4; ++m)
        #pragma unroll
        for (int n = 0; n < 4; ++n)
          acc[m][n] = __builtin_amdgcn_mfma_f32_16x16x32_bf16(a[m], b[n], acc[m][n], 0, 0, 0);
    }
  };

  stage(0, 0);
  for (int kt = 0; kt < NKT; ++kt) {
    const int cur = kt & 1;
    if (kt + 1 < NKT) {
      stage(cur ^ 1, kt + 1);
      asm volatile("s_waitcnt vmcnt(8)" ::: "memory");  // current tile done; prefetch stays in flight
    } else {
      asm volatile("s_waitcnt vmcnt(0)" ::: "memory");
    }
    wg_barrier();
    compute(cur);
    wg_barrier();
  }

  // ---- epilogue: bias (+scale for Q), bf16, coalesce via LDS [128][136] tile ----
  const float* bias = (z == 0) ? bq : (z == 1) ? bk : bv;
  const float scale = (z == 0) ? 0.04562280215f : 1.0f;  // log2(e)/sqrt(1000) folded into Q
  unsigned short* T = (unsigned short*)lds;              // 128*136*2 = 34816B
  const int rbase = (wave >> 1) * 64 + (lane >> 4) * 4;  // local row (m / s dim)
  const int cbase = (wave & 1) * 64 + (lane & 15);       // local col (n / a dim)
  float bvals[4];
  #pragma unroll
  for (int n = 0; n < 4; ++n) bvals[n] = bias[n0 + cbase + n * 16];
  #pragma unroll
  for (int m = 0; m < 4; ++m) {
    #pragma unroll
    for (int n = 0; n < 4; ++n) {
      const int cl = cbase + n * 16;
      #pragma unroll
      for (int j = 0; j < 4; ++j) {
        const int rl = rbase + m * 16 + j;
        const unsigned short h = f2bf((acc[m][n][j] + bvals[n]) * scale);
        if (z == 2) T[cl * 136 + rl] = h;   // transposed: [a_local][s_local]
        else        T[rl * 136 + cl] = h;   // natural:    [s_local][a_local]
      }
    }
  }
  wg_barrier();
  #pragma unroll
  for (int i = 0; i < 8; ++i) {
    int c2 = i * 256 + tid;                 // 2048 chunks of 16B
    int rr = c2 >> 4, ch = (c2 & 15) * 8;
    s16x8 chunk = *(const s16x8*)&T[rr * 136 + ch];
    if (z == 2) {
      // rr = a_local, ch.. = s_local. 16B chunk never straddles a batch (8 | 1000).
      const int rowg0 = m0 + ch;
      const int bb2 = rowg0 / SS, ss2 = rowg0 - bb2 * SS;
      *(s16x8*)&VTo[(size_t)bb2 * AA * SS + (size_t)(n0 + rr) * SS + ss2] = chunk;
    } else {
      unsigned short* O = (z == 0) ? Qo : Ko;
      *(s16x8*)&O[(size_t)(m0 + rr) * AA + n0 + ch] = chunk;
    }
  }
}

// ---------------------------------------------------------------- fused causal attention
// K-SPLIT balance (T=20): grid 256, b=L&31 (XCD pin), g=7-(L>>5) (long first).
// Phase1: own 128-row chunk g, k-tiles [0, min(4(g+1),20)); g<=4 complete (final
// store), g>=5 partial -> slot A. Phase2 (g<=2): partner r=7-g, its k-tail
// [20, 4(r+1)) -> partial slot B. Loop totals {16,16,16,16,20,20,20,20}.
// K+V double-buffered (138KB LDS, 1 block/CU, 8 waves): stage(t+1) BEFORE compute(t).
__global__ __launch_bounds__(512, 2) void attn_kernel(
    const unsigned short* __restrict__ Qs, const unsigned short* __restrict__ Ks,
    const unsigned short* __restrict__ VT, float* __restrict__ out,
    float* __restrict__ part) {
  constexpr int KVB = 32;
  __shared__ unsigned char ldsK[2][KVB * AA * 2];   // 2 x 32KB, XOR-swizzled rows
  __shared__ unsigned char ldsV[2][AA * KVB * 2];   // 2 x 32KB, pair-layout swizzled
  __shared__ unsigned char ldsP[8][16 * 80];        // per-wave P bounce, 10KB

  const int tid = threadIdx.x, lane = tid & 63, wave = tid >> 6;
  const int L = blockIdx.x;
  const int b = L & 31;                      // XCD = L%8 = b%8
  const int g = 7 - (L >> 5);                // own chunk; g=7 (20 iters) dispatches first

  // hoisted per-lane stage offsets (elements); 4096 chunks over 512 threads
  const unsigned short* kbase = Ks + (size_t)b * SS * AA;
  const unsigned short* vbase = VT + (size_t)b * AA * SS;
  unsigned int koff[4], voff[4];
  #pragma unroll
  for (int i = 0; i < 4; ++i) {
    int c = i * 512 + tid;                   // 2048 chunks
    int r = c >> 6;                          // K row 0..31
    int cb = ((c & 63) * 16) ^ ((r & 7) << 4);
    koff[i] = r * AA + (cb >> 1);
    int pair = c >> 3;
    int within = (c & 7) * 16;
    int half = within >> 6;
    int kb = (within & 63) ^ ((pair & 3) << 4);
    int a_ = pair * 2 + half;
    voff[i] = a_ * SS + (kb >> 1);
  }

  auto stageKV = [&](int buf, int t) {
    #pragma unroll
    for (int i = 0; i < 4; ++i)
      gl_lds16(kbase + koff[i] + (unsigned)(t * (KVB * AA)),
               &ldsK[buf][(i * 512 + tid) * 16]);
    #pragma unroll
    for (int i = 0; i < 4; ++i)
      gl_lds16(vbase + voff[i] + (unsigned)(t * KVB),
               &ldsV[buf][(i * 512 + tid) * 16]);
  };

  // phase descriptors: {rowbase, t0, t1, mode(0 final,1 slotA,2 slotB), chunkidx}
  int ownN = 4 * (g + 1);
  int rb_[2], t0_[2], t1_[2], md_[2], cx_[2];
  int nph = 1;
  rb_[0] = 128 * g; t0_[0] = 0; t1_[0] = (ownN < 20) ? ownN : 20;
  md_[0] = (g <= 4) ? 0 : 1; cx_[0] = g - 5;
  if (g <= 2) {
    int r = 7 - g;
    rb_[1] = 128 * r; t0_[1] = 20; t1_[1] = 4 * (r + 1); md_[1] = 2; cx_[1] = r - 5;
    nph = 2;
  }

  for (int ph = 0; ph < nph; ++ph) {
    const int rowbase = rb_[ph], tbeg = t0_[ph], tend = t1_[ph];
    const int mode = md_[ph], cidx = cx_[ph];
    const int q0w = rowbase + wave * 16;

    // Q fragments for this phase's rows
    s16x8 qf[16];
    {
      int qrow = q0w + (lane & 15);
      int qr = qrow < SS ? qrow : SS - 1;
      const unsigned short* qp = Qs + (size_t)(b * SS + qr) * AA + (lane >> 4) * 8;
      #pragma unroll
      for (int f = 0; f < 16; ++f) qf[f] = *(const s16x8*)(qp + f * 32);
    }

    f32x4 o[32];
    #pragma unroll
    for (int n = 0; n < 32; ++n) o[n] = f32x4{0.f, 0.f, 0.f, 0.f};
    float mrun[4], ps[4];
    #pragma unroll
    for (int j = 0; j < 4; ++j) { mrun[j] = -__builtin_inff(); ps[j] = 0.f; }

    stageKV(0, tbeg);
    asm volatile("s_waitcnt vmcnt(0)" ::: "memory");
    wg_barrier();

    for (int t = tbeg; t < tend; ++t) {
      const int cur = (t - tbeg) & 1;
      const int k0 = t * KVB;
      if (t + 1 < tend) stageKV(cur ^ 1, t + 1);   // prefetch BEFORE compute

      // ---- QK^T: 4 independent 8-deep MFMA chains ----
      f32x4 p0a = {0.f, 0.f, 0.f, 0.f}, p0b = {0.f, 0.f, 0.f, 0.f};
      f32x4 p1a = {0.f, 0.f, 0.f, 0.f}, p1b = {0.f, 0.f, 0.f, 0.f};
      {
        const int r0 = lane & 15;
        const int sw = (r0 & 7) << 4;
        const int kb16 = (lane >> 4) * 16;
        const int rb0 = r0 << 10, rb1 = (r0 + 16) << 10;
        #pragma unroll
        for (int f = 0; f < 8; ++f) {
          const int offA = f * 64 + kb16;
          const int offB = (f + 8) * 64 + kb16;
          s16x8 k0A = *(const s16x8*)&ldsK[cur][rb0 + (offA ^ sw)];
          s16x8 k1A = *(const s16x8*)&ldsK[cur][rb1 + (offA ^ sw)];
          s16x8 k0B = *(const s16x8*)&ldsK[cur][rb0 + (offB ^ sw)];
          s16x8 k1B = *(const s16x8*)&ldsK[cur][rb1 + (offB ^ sw)];
          p0a = __builtin_amdgcn_mfma_f32_16x16x32_bf16(qf[f], k0A, p0a, 0, 0, 0);
          p1a = __builtin_amdgcn_mfma_f32_16x16x32_bf16(qf[f], k1A, p1a, 0, 0, 0);
          p0b = __builtin_amdgcn_mfma_f32_16x16x32_bf16(qf[f + 8], k0B, p0b, 0, 0, 0);
          p1b = __builtin_amdgcn_mfma_f32_16x16x32_bf16(qf[f + 8], k1B, p1b, 0, 0, 0);
        }
      }
      f32x4 p0 = p0a + p0b, p1 = p1a + p1b;

      // ---- causal mask + defer-max online softmax ----
      const int kcol = k0 + (lane & 15);
      float lm[4];
      #pragma unroll
      for (int j = 0; j < 4; ++j) {
        const int q = q0w + (lane >> 4) * 4 + j;
        float s0 = p0[j], s1 = p1[j];
        if (kcol > q || kcol >= SS) s0 = -__builtin_inff();
        if (kcol + 16 > q || kcol + 16 >= SS) s1 = -__builtin_inff();
        p0[j] = s0; p1[j] = s1;
        lm[j] = fmaxf(s0, s1);
      }
      const int myneed = (lm[0] > mrun[0] + 8.f) | (lm[1] > mrun[1] + 8.f) |
                         (lm[2] > mrun[2] + 8.f) | (lm[3] > mrun[3] + 8.f);
      if (__any(myneed)) {
        float rm[4] = {lm[0], lm[1], lm[2], lm[3]};
        #pragma unroll
        for (int st = 1; st <= 8; st <<= 1)
          #pragma unroll
          for (int j = 0; j < 4; ++j) rm[j] = fmaxf(rm[j], __shfl_xor(rm[j], st));
        float corr[4];
        #pragma unroll
        for (int j = 0; j < 4; ++j) {
          const float mnew = fmaxf(mrun[j], rm[j]);
          corr[j] = fast_exp2(mrun[j] - mnew);    // exp2(-inf)=0 on first tile
          mrun[j] = mnew;
          ps[j] *= corr[j];
        }
        #pragma unroll
        for (int n = 0; n < 32; ++n)
          #pragma unroll
          for (int j = 0; j < 4; ++j) o[n][j] *= corr[j];
      }
      #pragma unroll
      for (int j = 0; j < 4; ++j) {
        const float e0 = fast_exp2(p0[j] - mrun[j]);
        const float e1 = fast_exp2(p1[j] - mrun[j]);
        ps[j] += e0 + e1;
        p0[j] = e0; p1[j] = e1;
      }

      // ---- P -> bf16 -> wave-private LDS -> A-fragment ----
      {
        unsigned short* pb = (unsigned short*)&ldsP[wave][0];
        const int prow = (lane >> 4) * 4, pc = lane & 15;
        #pragma unroll
        for (int j = 0; j < 4; ++j) {
          pb[(prow + j) * 40 + pc]      = f2bf(p0[j]);
          pb[(prow + j) * 40 + pc + 16] = f2bf(p1[j]);
        }
      }
      s16x8 pa;
      {
        const unsigned char* pp = &ldsP[wave][(lane & 15) * 80 + (lane >> 4) * 16];
        s16x4 lo = *(const s16x4*)pp;
        s16x4 hi = *(const s16x4*)(pp + 8);
        pa = s16x8{lo[0], lo[1], lo[2], lo[3], hi[0], hi[1], hi[2], hi[3]};
      }

      // ---- PV ----
      #pragma unroll
      for (int n = 0; n < 32; ++n) {
        const int a_ = n * 16 + (lane & 15);
        const int pair = a_ >> 1;
        const int off = pair * 128 + (a_ & 1) * 64 + (((lane >> 4) * 16) ^ ((pair & 3) << 4));
        s16x8 vb = *(const s16x8*)&ldsV[cur][off];
        o[n] = __builtin_amdgcn_mfma_f32_16x16x32_bf16(pa, vb, o[n], 0, 0, 0);
      }

      asm volatile("s_waitcnt vmcnt(0)" ::: "memory");  // prefetch landed (covered by compute)
      wg_barrier();
    }

    // ---- finalize phase: reduce l; final store or partial store ----
    #pragma unroll
    for (int st = 1; st <= 8; st <<= 1)
      #pragma unroll
      for (int j = 0; j < 4; ++j) ps[j] += __shfl_xor(ps[j], st);

    if (mode == 0) {
      #pragma unroll
      for (int j = 0; j < 4; ++j) {
        const int q = q0w + (lane >> 4) * 4 + j;
        if (q < SS) {
          const float inv = 1.0f / ps[j];
          float* op = out + (size_t)(b * SS + q) * AA + (lane & 15);
          #pragma unroll
          for (int n = 0; n < 32; ++n) op[n * 16] = o[n][j] * inv;
        }
      }
    } else {
      const int slot = mode - 1;
      #pragma unroll
      for (int j = 0; j < 4; ++j) {
        const int rl = wave * 16 + (lane >> 4) * 4 + j;       // row within chunk
        const size_t idx = (size_t)slot * PROWS + ((size_t)(b * 3 + cidx) * 128 + rl);
        float* po = part + idx * 512 + (lane & 15);
        #pragma unroll
        for (int n = 0; n < 32; ++n) po[n * 16] = o[n][j];    // raw (unnormalized)
        if ((lane & 15) == 0) {
          float* pml = part + ML_OFF + idx * 2;
          pml[0] = mrun[j];
          pml[1] = ps[j];
        }
      }
    }
  }
}

// ---------------------------------------------------------------- combine partials
// rows 640..999 of each batch (chunks 5..7): merge slot A (k head) + slot B (k tail).
__global__ __launch_bounds__(256) void combine_kernel(const float* __restrict__ part,
                                                      float* __restrict__ out) {
  const int rid = blockIdx.x * 2 + (threadIdx.x >> 7);   // 0..12287
  const int t = threadIdx.x & 127;                       // float4 col index
  const int b = rid / 384;
  const int rem = rid - b * 384;
  const int c = rem >> 7, row = rem & 127;
  const int q = (c + 5) * 128 + row;
  if (q >= SS) return;
  const float* mlA = part + ML_OFF + (size_t)rid * 2;
  const float* mlB = part + ML_OFF + ((size_t)PROWS + rid) * 2;
  const float mA = mlA[0], lA = mlA[1];
  const float mB = mlB[0], lB = mlB[1];
  const float m = fmaxf(mA, mB);
  const float sA = fast_exp2(mA - m), sB = fast_exp2(mB - m);
  const float inv = 1.0f / (lA * sA + lB * sB);
  const float4 a = ((const float4*)(part + (size_t)rid * 512))[t];
  const float4 d = ((const float4*)(part + ((size_t)PROWS + rid) * 512))[t];
  float4 r;
  r.x = (a.x * sA + d.x * sB) * inv;
  r.y = (a.y * sA + d.y * sB) * inv;
  r.z = (a.z * sA + d.z * sB) * inv;
  r.w = (a.w * sA + d.w * sB) * inv;
  ((float4*)(out + ((size_t)b * SS + q) * AA))[t] = r;
}

// ---------------------------------------------------------------- launch
extern "C" void kernel_launch(void* const* d_in, const int* in_sizes, int n_in,
                              void* d_out, int out_size, void* d_ws, size_t ws_size,
                              hipStream_t stream) {
  const float* x  = (const float*)d_in[0];
  const float* Wk = (const float*)d_in[1];
  const float* bk = (const float*)d_in[2];
  const float* Wq = (const float*)d_in[3];
  const float* bq = (const float*)d_in[4];
  const float* Wv = (const float*)d_in[5];
  const float* bv = (const float*)d_in[6];

  char* ws = (char*)d_ws;
  unsigned short* X16 = (unsigned short*)(ws + OFF_X16);
  unsigned short* Qw  = (unsigned short*)(ws + OFF_Q);
  unsigned short* Kw  = (unsigned short*)(ws + OFF_K);
  unsigned short* VTw = (unsigned short*)(ws + OFF_VT);
  unsigned short* WT  = (unsigned short*)(ws + OFF_WT);
  float* Part = (float*)(ws + OFF_X16);   // X16 region dead after proj

  x_to_bf16_kernel<<<dim3(2048), dim3(256), 0, stream>>>(x, X16);
  wt_kernel<<<dim3(EE / 64, AA / 64, 3), dim3(256), 0, stream>>>(Wq, Wk, Wv, WT);
  proj_kernel<<<dim3(3000), dim3(256), 0, stream>>>(
      X16, WT, bq, bk, bv, Qw, Kw, VTw);
  attn_kernel<<<dim3(256), dim3(512), 0, stream>>>(Qw, Kw, VTw, (float*)d_out, Part);
  combine_kernel<<<dim3(PROWS / 2), dim3(256), 0, stream>>>(Part, (float*)d_out);
}

// Round 20
// 276.516 us; speedup vs baseline: 1.3830x; 1.0662x over previous
//
#include <hip/hip_runtime.h>
#include <hip/hip_bf16.h>
#include <stdint.h>

#define DEVI __device__ __forceinline__

typedef short s16x8 __attribute__((ext_vector_type(8)));
typedef short s16x4 __attribute__((ext_vector_type(4)));
typedef float f32x4 __attribute__((ext_vector_type(4)));

static constexpr int BB = 32, SS = 1000, EE = 1024, AA = 512;
static constexpr int MM = BB * SS;  // 32000

// workspace layout (bytes)
static constexpr size_t OFF_X16 = 0;                                   // [M][E] bf16 (dead after proj -> attn partials)
static constexpr size_t OFF_Q   = OFF_X16 + (size_t)MM * EE * 2;       // [M][A] bf16 (pre-scaled by log2e/sqrt(S))
static constexpr size_t OFF_K   = OFF_Q  + (size_t)MM * AA * 2;        // [M][A] bf16
static constexpr size_t OFF_VT  = OFF_K  + (size_t)MM * AA * 2;        // [B][A][S] bf16
static constexpr size_t OFF_WT  = OFF_VT + (size_t)BB * AA * SS * 2;   // 3 x [A][E] bf16

// attn K-split partials (inside X16 region)
static constexpr int PROWS = BB * 3 * 128;                 // 12288 rows per slot
static constexpr size_t ML_OFF = (size_t)2 * PROWS * 512;  // floats

DEVI unsigned short f2bf(float f) {
  union { float f; unsigned int u; } c; c.f = f;
  unsigned int u = c.u + 0x7fffu + ((c.u >> 16) & 1u);
  return (unsigned short)(u >> 16);
}

DEVI void gl_lds16(const void* g, void* l) {
  __builtin_amdgcn_global_load_lds(
      (const __attribute__((address_space(1))) unsigned int*)g,
      (__attribute__((address_space(3))) unsigned int*)l, 16, 0, 0);
}

DEVI void wg_barrier() {
  asm volatile("" ::: "memory");
  __builtin_amdgcn_s_barrier();
  asm volatile("" ::: "memory");
}

DEVI float fast_exp2(float x) {
#if __has_builtin(__builtin_amdgcn_exp2f)
  return __builtin_amdgcn_exp2f(x);
#else
  return __builtin_exp2f(x);
#endif
}

// ---------------------------------------------------------------- prep kernels
__global__ __launch_bounds__(256) void x_to_bf16_kernel(const float* __restrict__ x,
                                                        unsigned short* __restrict__ x16) {
  const long n4 = (long)MM * EE / 4;
  long i = (long)blockIdx.x * blockDim.x + threadIdx.x;
  const long stride = (long)gridDim.x * blockDim.x;
  for (; i < n4; i += stride) {
    const float4 v = ((const float4*)x)[i];
    ushort4 o;
    o.x = f2bf(v.x); o.y = f2bf(v.y); o.z = f2bf(v.z); o.w = f2bf(v.w);
    ((ushort4*)x16)[i] = o;
  }
}

__global__ __launch_bounds__(256) void wt_kernel(const float* __restrict__ Wq,
                                                 const float* __restrict__ Wk,
                                                 const float* __restrict__ Wv,
                                                 unsigned short* __restrict__ WT) {
  const float* W = (blockIdx.z == 0) ? Wq : (blockIdx.z == 1) ? Wk : Wv;
  unsigned short* out = WT + (size_t)blockIdx.z * AA * EE;
  __shared__ unsigned short t[64][65];
  const int k0 = blockIdx.x * 64, n0 = blockIdx.y * 64;
  #pragma unroll
  for (int i = 0; i < 16; ++i) {
    int idx = i * 256 + threadIdx.x;
    int r = idx >> 6, c = idx & 63;
    t[r][c] = f2bf(W[(size_t)(k0 + r) * AA + n0 + c]);
  }
  __syncthreads();
  #pragma unroll
  for (int i = 0; i < 16; ++i) {
    int idx = i * 256 + threadIdx.x;
    int r = idx >> 6, c = idx & 63;
    out[(size_t)(n0 + r) * EE + k0 + c] = t[c][r];
  }
}

// ---------------------------------------------------------------- QKV projection
// 256x256 tile, BK=64, 8 waves (2M x 4N), 8-phase schedule (T3-class):
// per phase: 12 ds_read (compiler lgkmcnt) -> 1 half-tile gl_lds stage ->
// s_barrier -> setprio(1) -> 16 MFMA -> setprio(0) -> [vmcnt(0) at group close]
// -> s_barrier. Fixed buffers by K-tile parity: buf0=even, buf1=odd.
// Group A (phases 1-4): compute tile 2J (buf0), stage tile 2J+1 halves -> buf1
// (buf1's old tile last read at prev group-B close barrier). Group B: compute
// tile 2J+1, stage tile 2J+2 -> buf0. vmcnt(0) at each group close has >=3
// phases of lead. Swizzle + staging math carried verbatim from verified 128^2.
// Grid 750 1D, XCD-panel-pinned (6 blocks/panel, groups of 48).
#define PROJ_PHASE(BUF, QA, QB, SKT, SWH, SBUF, DOVM)                          \
  {                                                                            \
    if ((QB) == 0) {                                                           \
      _Pragma("unroll") for (int kk = 0; kk < 2; ++kk) {                       \
        _Pragma("unroll") for (int f = 0; f < 4; ++f) {                        \
          int row = wm * 128 + ((QA) * 4 + f) * 16 + (lane & 15);              \
          int cb = (kk * 64 + (lane >> 4) * 16) ^ ((row & 7) << 4);            \
          aR[kk][f] = *(const s16x8*)(lds + (BUF) * 32768 + row * 128 + cb);   \
        }                                                                      \
      }                                                                        \
    }                                                                          \
    s16x8 bR[2][2];                                                            \
    _Pragma("unroll") for (int kk = 0; kk < 2; ++kk) {                         \
      _Pragma("unroll") for (int g2 = 0; g2 < 2; ++g2) {                       \
        int row = wn * 64 + ((QB) * 2 + g2) * 16 + (lane & 15);                \
        int cb = (kk * 64 + (lane >> 4) * 16) ^ ((row & 7) << 4);              \
        bR[kk][g2] = *(const s16x8*)(lds + 65536 + (BUF) * 32768 + row * 128 + cb); \
      }                                                                        \
    }                                                                          \
    if ((SKT) >= 0) stage_half(SBUF, SKT, SWH);                                \
    wg_barrier();                                                              \
    __builtin_amdgcn_s_setprio(1);                                             \
    _Pragma("unroll") for (int kk = 0; kk < 2; ++kk) {                         \
      _Pragma("unroll") for (int f = 0; f < 4; ++f) {                          \
        _Pragma("unroll") for (int g2 = 0; g2 < 2; ++g2) {                     \
          acc[(QA) * 4 + f][(QB) * 2 + g2] = __builtin_amdgcn_mfma_f32_16x16x32_bf16( \
              aR[kk][f], bR[kk][g2], acc[(QA) * 4 + f][(QB) * 2 + g2], 0, 0, 0); \
        }                                                                      \
      }                                                                        \
    }                                                                          \
    __builtin_amdgcn_s_setprio(0);                                             \
    if (DOVM) asm volatile("s_waitcnt vmcnt(0)" ::: "memory");                 \
    wg_barrier();                                                              \
  }

__global__ __launch_bounds__(512, 2) void proj_kernel(
    const unsigned short* __restrict__ X16, const unsigned short* __restrict__ WT,
    const float* __restrict__ bq, const float* __restrict__ bk, const float* __restrict__ bv,
    unsigned short* __restrict__ Qo, unsigned short* __restrict__ Ko,
    unsigned short* __restrict__ VTo) {
  __shared__ unsigned char lds[131072];  // A: [2 buf][256 rows][128B] @0 | B @65536
  const int tid = threadIdx.x, lane = tid & 63, wave = tid >> 6;
  const int wm = wave >> 2, wn = wave & 3;

  const int phys = blockIdx.x;
  int p, r;
  if (phys < 720) { int g = phys / 48, w = phys % 48; p = g * 8 + (w & 7); r = w >> 3; }
  else            { int w = phys - 720; p = 120 + w % 5; r = w / 5; }
  const int z = r >> 1, nidx = r & 1;
  const int m0 = p * 256, n0 = nidx * 256;
  const unsigned short* Wz = WT + (size_t)z * AA * EE;

  f32x4 acc[8][4];
  #pragma unroll
  for (int i = 0; i < 8; ++i)
    #pragma unroll
    for (int j = 0; j < 4; ++j) acc[i][j] = f32x4{0.f, 0.f, 0.f, 0.f};

  // hoisted per-thread stage chunk constants (2 chunks per half)
  unsigned int offH[2];
  #pragma unroll
  for (int i = 0; i < 2; ++i) {
    int c = i * 512 + tid;                 // 0..1023
    int rl = c >> 3, s = c & 7;
    int cb = (s * 16) ^ ((rl & 7) << 4);   // pre-swizzled source column (bytes)
    offH[i] = (unsigned)(rl * EE + (cb >> 1));
  }
  // stage one half-tile: which 0:A-h0 1:A-h1 2:B-h0 3:B-h1
  auto stage_half = [&](int buf, int kt, int which) {
    const int h = which & 1;
    const int isB = which >> 1;
    const unsigned short* srcb = isB ? (Wz + (size_t)(n0 + h * 128) * EE + kt * 64)
                                     : (X16 + (size_t)(m0 + h * 128) * EE + kt * 64);
    unsigned char* dstb = lds + (isB ? 65536 : 0) + buf * 32768 + h * 16384;
    #pragma unroll
    for (int i = 0; i < 2; ++i)
      gl_lds16(srcb + offH[i], dstb + (i * 512 + tid) * 16);
  };

  // prologue: tile 0 -> buf0 (4 halves)
  stage_half(0, 0, 0); stage_half(0, 0, 1); stage_half(0, 0, 2); stage_half(0, 0, 3);
  asm volatile("s_waitcnt vmcnt(0)" ::: "memory");
  wg_barrier();

  s16x8 aR[2][4];
  for (int J = 0; J < 8; ++J) {
    const int t1 = 2 * J + 1;
    const int t2 = (J < 7) ? (2 * J + 2) : -1;
    // Group A: tile 2J (buf0); stage tile t1 -> buf1
    PROJ_PHASE(0, 0, 0, t1, 0, 1, false)
    PROJ_PHASE(0, 0, 1, t1, 1, 1, false)
    PROJ_PHASE(0, 1, 0, t1, 2, 1, false)
    PROJ_PHASE(0, 1, 1, t1, 3, 1, true)
    // Group B: tile 2J+1 (buf1); stage tile t2 -> buf0
    PROJ_PHASE(1, 0, 0, t2, 0, 0, false)
    PROJ_PHASE(1, 0, 1, t2, 1, 0, false)
    PROJ_PHASE(1, 1, 0, t2, 2, 0, false)
    PROJ_PHASE(1, 1, 1, t2, 3, 0, true)
  }

  // ---- epilogue: bias (+scale for Q), bf16, LDS-coalesced in two passes ----
  const float* bias = (z == 0) ? bq : (z == 1) ? bk : bv;
  const float scale = (z == 0) ? 0.04562280215f : 1.0f;
  unsigned short* T = (unsigned short*)lds;   // [128][264] halfwords = 67.6KB
  float bv4[4];
  #pragma unroll
  for (int nf = 0; nf < 4; ++nf) bv4[nf] = bias[n0 + wn * 64 + nf * 16 + (lane & 15)];

  if (z != 2) {
    unsigned short* O = (z == 0) ? Qo : Ko;
    #pragma unroll
    for (int h = 0; h < 2; ++h) {
      if (wm == h) {
        #pragma unroll
        for (int mf = 0; mf < 8; ++mf)
          #pragma unroll
          for (int nf = 0; nf < 4; ++nf) {
            const int col = wn * 64 + nf * 16 + (lane & 15);
            #pragma unroll
            for (int j = 0; j < 4; ++j) {
              const int rr = mf * 16 + (lane >> 4) * 4 + j;
              T[rr * 264 + col] = f2bf((acc[mf][nf][j] + bv4[nf]) * scale);
            }
          }
      }
      wg_barrier();
      #pragma unroll
      for (int i = 0; i < 8; ++i) {
        int c2 = i * 512 + tid;                  // 4096 chunks of 16B
        int rr = c2 >> 5, ch = (c2 & 31) * 8;
        s16x8 chunk = *(const s16x8*)&T[rr * 264 + ch];
        *(s16x8*)&O[(size_t)(m0 + h * 128 + rr) * AA + n0 + ch] = chunk;
      }
      wg_barrier();
    }
  } else {
    #pragma unroll
    for (int h = 0; h < 2; ++h) {
      if ((wn >> 1) == h) {
        #pragma unroll
        for (int mf = 0; mf < 8; ++mf)
          #pragma unroll
          for (int nf = 0; nf < 4; ++nf) {
            const int al = (wn & 1) * 64 + nf * 16 + (lane & 15);   // a_local 0..127
            #pragma unroll
            for (int j = 0; j < 4; ++j) {
              const int sl = wm * 128 + mf * 16 + (lane >> 4) * 4 + j;  // s_local 0..255
              T[al * 264 + sl] = f2bf(acc[mf][nf][j] + bv4[nf]);
            }
          }
      }
      wg_barrier();
      #pragma unroll
      for (int i = 0; i < 8; ++i) {
        int c2 = i * 512 + tid;
        int rr = c2 >> 5, ch = (c2 & 31) * 8;    // rr: a_local, ch: s_local start
        s16x8 chunk = *(const s16x8*)&T[rr * 264 + ch];
        const int rowg0 = m0 + ch;               // 16B never straddles batch (8|1000)
        const int bb2 = rowg0 / SS, ss2 = rowg0 - bb2 * SS;
        *(s16x8*)&VTo[(size_t)bb2 * AA * SS + (size_t)(n0 + h * 128 + rr) * SS + ss2] = chunk;
      }
      wg_barrier();
    }
  }
}

// ---------------------------------------------------------------- fused causal attention
// (unchanged R18: K-split T=20, XCD pin, K+V dbuf, prefetch-before-compute)
__global__ __launch_bounds__(512, 2) void attn_kernel(
    const unsigned short* __restrict__ Qs, const unsigned short* __restrict__ Ks,
    const unsigned short* __restrict__ VT, float* __restrict__ out,
    float* __restrict__ part) {
  constexpr int KVB = 32;
  __shared__ unsigned char ldsK[2][KVB * AA * 2];
  __shared__ unsigned char ldsV[2][AA * KVB * 2];
  __shared__ unsigned char ldsP[8][16 * 80];

  const int tid = threadIdx.x, lane = tid & 63, wave = tid >> 6;
  const int L = blockIdx.x;
  const int b = L & 31;
  const int g = 7 - (L >> 5);

  const unsigned short* kbase = Ks + (size_t)b * SS * AA;
  const unsigned short* vbase = VT + (size_t)b * AA * SS;
  unsigned int koff[4], voff[4];
  #pragma unroll
  for (int i = 0; i < 4; ++i) {
    int c = i * 512 + tid;
    int r = c >> 6;
    int cb = ((c & 63) * 16) ^ ((r & 7) << 4);
    koff[i] = r * AA + (cb >> 1);
    int pair = c >> 3;
    int within = (c & 7) * 16;
    int half = within >> 6;
    int kb = (within & 63) ^ ((pair & 3) << 4);
    int a_ = pair * 2 + half;
    voff[i] = a_ * SS + (kb >> 1);
  }

  auto stageKV = [&](int buf, int t) {
    #pragma unroll
    for (int i = 0; i < 4; ++i)
      gl_lds16(kbase + koff[i] + (unsigned)(t * (KVB * AA)),
               &ldsK[buf][(i * 512 + tid) * 16]);
    #pragma unroll
    for (int i = 0; i < 4; ++i)
      gl_lds16(vbase + voff[i] + (unsigned)(t * KVB),
               &ldsV[buf][(i * 512 + tid) * 16]);
  };

  int ownN = 4 * (g + 1);
  int rb_[2], t0_[2], t1_[2], md_[2], cx_[2];
  int nph = 1;
  rb_[0] = 128 * g; t0_[0] = 0; t1_[0] = (ownN < 20) ? ownN : 20;
  md_[0] = (g <= 4) ? 0 : 1; cx_[0] = g - 5;
  if (g <= 2) {
    int r = 7 - g;
    rb_[1] = 128 * r; t0_[1] = 20; t1_[1] = 4 * (r + 1); md_[1] = 2; cx_[1] = r - 5;
    nph = 2;
  }

  for (int ph = 0; ph < nph; ++ph) {
    const int rowbase = rb_[ph], tbeg = t0_[ph], tend = t1_[ph];
    const int mode = md_[ph], cidx = cx_[ph];
    const int q0w = rowbase + wave * 16;

    s16x8 qf[16];
    {
      int qrow = q0w + (lane & 15);
      int qr = qrow < SS ? qrow : SS - 1;
      const unsigned short* qp = Qs + (size_t)(b * SS + qr) * AA + (lane >> 4) * 8;
      #pragma unroll
      for (int f = 0; f < 16; ++f) qf[f] = *(const s16x8*)(qp + f * 32);
    }

    f32x4 o[32];
    #pragma unroll
    for (int n = 0; n < 32; ++n) o[n] = f32x4{0.f, 0.f, 0.f, 0.f};
    float mrun[4], ps[4];
    #pragma unroll
    for (int j = 0; j < 4; ++j) { mrun[j] = -__builtin_inff(); ps[j] = 0.f; }

    stageKV(0, tbeg);
    asm volatile("s_waitcnt vmcnt(0)" ::: "memory");
    wg_barrier();

    for (int t = tbeg; t < tend; ++t) {
      const int cur = (t - tbeg) & 1;
      const int k0 = t * KVB;
      if (t + 1 < tend) stageKV(cur ^ 1, t + 1);

      f32x4 p0a = {0.f, 0.f, 0.f, 0.f}, p0b = {0.f, 0.f, 0.f, 0.f};
      f32x4 p1a = {0.f, 0.f, 0.f, 0.f}, p1b = {0.f, 0.f, 0.f, 0.f};
      {
        const int r0 = lane & 15;
        const int sw = (r0 & 7) << 4;
        const int kb16 = (lane >> 4) * 16;
        const int rb0 = r0 << 10, rb1 = (r0 + 16) << 10;
        #pragma unroll
        for (int f = 0; f < 8; ++f) {
          const int offA = f * 64 + kb16;
          const int offB = (f + 8) * 64 + kb16;
          s16x8 k0A = *(const s16x8*)&ldsK[cur][rb0 + (offA ^ sw)];
          s16x8 k1A = *(const s16x8*)&ldsK[cur][rb1 + (offA ^ sw)];
          s16x8 k0B = *(const s16x8*)&ldsK[cur][rb0 + (offB ^ sw)];
          s16x8 k1B = *(const s16x8*)&ldsK[cur][rb1 + (offB ^ sw)];
          p0a = __builtin_amdgcn_mfma_f32_16x16x32_bf16(qf[f], k0A, p0a, 0, 0, 0);
          p1a = __builtin_amdgcn_mfma_f32_16x16x32_bf16(qf[f], k1A, p1a, 0, 0, 0);
          p0b = __builtin_amdgcn_mfma_f32_16x16x32_bf16(qf[f + 8], k0B, p0b, 0, 0, 0);
          p1b = __builtin_amdgcn_mfma_f32_16x16x32_bf16(qf[f + 8], k1B, p1b, 0, 0, 0);
        }
      }
      f32x4 p0 = p0a + p0b, p1 = p1a + p1b;

      const int kcol = k0 + (lane & 15);
      float lm[4];
      #pragma unroll
      for (int j = 0; j < 4; ++j) {
        const int q = q0w + (lane >> 4) * 4 + j;
        float s0 = p0[j], s1 = p1[j];
        if (kcol > q || kcol >= SS) s0 = -__builtin_inff();
        if (kcol + 16 > q || kcol + 16 >= SS) s1 = -__builtin_inff();
        p0[j] = s0; p1[j] = s1;
        lm[j] = fmaxf(s0, s1);
      }
      const int myneed = (lm[0] > mrun[0] + 8.f) | (lm[1] > mrun[1] + 8.f) |
                         (lm[2] > mrun[2] + 8.f) | (lm[3] > mrun[3] + 8.f);
      if (__any(myneed)) {
        float rm[4] = {lm[0], lm[1], lm[2], lm[3]};
        #pragma unroll
        for (int st = 1; st <= 8; st <<= 1)
          #pragma unroll
          for (int j = 0; j < 4; ++j) rm[j] = fmaxf(rm[j], __shfl_xor(rm[j], st));
        float corr[4];
        #pragma unroll
        for (int j = 0; j < 4; ++j) {
          const float mnew = fmaxf(mrun[j], rm[j]);
          corr[j] = fast_exp2(mrun[j] - mnew);
          mrun[j] = mnew;
          ps[j] *= corr[j];
        }
        #pragma unroll
        for (int n = 0; n < 32; ++n)
          #pragma unroll
          for (int j = 0; j < 4; ++j) o[n][j] *= corr[j];
      }
      #pragma unroll
      for (int j = 0; j < 4; ++j) {
        const float e0 = fast_exp2(p0[j] - mrun[j]);
        const float e1 = fast_exp2(p1[j] - mrun[j]);
        ps[j] += e0 + e1;
        p0[j] = e0; p1[j] = e1;
      }

      {
        unsigned short* pb = (unsigned short*)&ldsP[wave][0];
        const int prow = (lane >> 4) * 4, pc = lane & 15;
        #pragma unroll
        for (int j = 0; j < 4; ++j) {
          pb[(prow + j) * 40 + pc]      = f2bf(p0[j]);
          pb[(prow + j) * 40 + pc + 16] = f2bf(p1[j]);
        }
      }
      s16x8 pa;
      {
        const unsigned char* pp = &ldsP[wave][(lane & 15) * 80 + (lane >> 4) * 16];
        s16x4 lo = *(const s16x4*)pp;
        s16x4 hi = *(const s16x4*)(pp + 8);
        pa = s16x8{lo[0], lo[1], lo[2], lo[3], hi[0], hi[1], hi[2], hi[3]};
      }

      #pragma unroll
      for (int n = 0; n < 32; ++n) {
        const int a_ = n * 16 + (lane & 15);
        const int pair = a_ >> 1;
        const int off = pair * 128 + (a_ & 1) * 64 + (((lane >> 4) * 16) ^ ((pair & 3) << 4));
        s16x8 vb = *(const s16x8*)&ldsV[cur][off];
        o[n] = __builtin_amdgcn_mfma_f32_16x16x32_bf16(pa, vb, o[n], 0, 0, 0);
      }

      asm volatile("s_waitcnt vmcnt(0)" ::: "memory");
      wg_barrier();
    }

    #pragma unroll
    for (int st = 1; st <= 8; st <<= 1)
      #pragma unroll
      for (int j = 0; j < 4; ++j) ps[j] += __shfl_xor(ps[j], st);

    if (mode == 0) {
      #pragma unroll
      for (int j = 0; j < 4; ++j) {
        const int q = q0w + (lane >> 4) * 4 + j;
        if (q < SS) {
          const float inv = 1.0f / ps[j];
          float* op = out + (size_t)(b * SS + q) * AA + (lane & 15);
          #pragma unroll
          for (int n = 0; n < 32; ++n) op[n * 16] = o[n][j] * inv;
        }
      }
    } else {
      const int slot = mode - 1;
      #pragma unroll
      for (int j = 0; j < 4; ++j) {
        const int rl = wave * 16 + (lane >> 4) * 4 + j;
        const size_t idx = (size_t)slot * PROWS + ((size_t)(b * 3 + cidx) * 128 + rl);
        float* po = part + idx * 512 + (lane & 15);
        #pragma unroll
        for (int n = 0; n < 32; ++n) po[n * 16] = o[n][j];
        if ((lane & 15) == 0) {
          float* pml = part + ML_OFF + idx * 2;
          pml[0] = mrun[j];
          pml[1] = ps[j];
        }
      }
    }
  }
}

// ---------------------------------------------------------------- combine partials
__global__ __launch_bounds__(256) void combine_kernel(const float* __restrict__ part,
                                                      float* __restrict__ out) {
  const int rid = blockIdx.x * 2 + (threadIdx.x >> 7);
  const int t = threadIdx.x & 127;
  const int b = rid / 384;
  const int rem = rid - b * 384;
  const int c = rem >> 7, row = rem & 127;
  const int q = (c + 5) * 128 + row;
  if (q >= SS) return;
  const float* mlA = part + ML_OFF + (size_t)rid * 2;
  const float* mlB = part + ML_OFF + ((size_t)PROWS + rid) * 2;
  const float mA = mlA[0], lA = mlA[1];
  const float mB = mlB[0], lB = mlB[1];
  const float m = fmaxf(mA, mB);
  const float sA = fast_exp2(mA - m), sB = fast_exp2(mB - m);
  const float inv = 1.0f / (lA * sA + lB * sB);
  const float4 a = ((const float4*)(part + (size_t)rid * 512))[t];
  const float4 d = ((const float4*)(part + ((size_t)PROWS + rid) * 512))[t];
  float4 r;
  r.x = (a.x * sA + d.x * sB) * inv;
  r.y = (a.y * sA + d.y * sB) * inv;
  r.z = (a.z * sA + d.z * sB) * inv;
  r.w = (a.w * sA + d.w * sB) * inv;
  ((float4*)(out + ((size_t)b * SS + q) * AA))[t] = r;
}

// ---------------------------------------------------------------- launch
extern "C" void kernel_launch(void* const* d_in, const int* in_sizes, int n_in,
                              void* d_out, int out_size, void* d_ws, size_t ws_size,
                              hipStream_t stream) {
  const float* x  = (const float*)d_in[0];
  const float* Wk = (const float*)d_in[1];
  const float* bk = (const float*)d_in[2];
  const float* Wq = (const float*)d_in[3];
  const float* bq = (const float*)d_in[4];
  const float* Wv = (const float*)d_in[5];
  const float* bv = (const float*)d_in[6];

  char* ws = (char*)d_ws;
  unsigned short* X16 = (unsigned short*)(ws + OFF_X16);
  unsigned short* Qw  = (unsigned short*)(ws + OFF_Q);
  unsigned short* Kw  = (unsigned short*)(ws + OFF_K);
  unsigned short* VTw = (unsigned short*)(ws + OFF_VT);
  unsigned short* WT  = (unsigned short*)(ws + OFF_WT);
  float* Part = (float*)(ws + OFF_X16);

  x_to_bf16_kernel<<<dim3(2048), dim3(256), 0, stream>>>(x, X16);
  wt_kernel<<<dim3(EE / 64, AA / 64, 3), dim3(256), 0, stream>>>(Wq, Wk, Wv, WT);
  proj_kernel<<<dim3(750), dim3(512), 0, stream>>>(
      X16, WT, bq, bk, bv, Qw, Kw, VTw);
  attn_kernel<<<dim3(256), dim3(512), 0, stream>>>(Qw, Kw, VTw, (float*)d_out, Part);
  combine_kernel<<<dim3(PROWS / 2), dim3(256), 0, stream>>>(Part, (float*)d_out);
}